// Round 9
// baseline (703.375 us; speedup 1.0000x reference)
//
#include <hip/hip_runtime.h>
#include <hip/hip_bf16.h>

#define R_REL 2016
#define MROWS 16384
#define HDIM  1024
#define EDIM  768
#define TOPK  28
#define KSEL  31
#define CAP   40
#define NPAD  2048
#define MPADR 2048

typedef unsigned short u16;
typedef __attribute__((ext_vector_type(8))) short short8;
typedef __attribute__((ext_vector_type(4))) float f32x4;

__device__ inline float bf2f(u16 u) {
  unsigned x = ((unsigned)u) << 16; float f;
  __builtin_memcpy(&f, &x, 4); return f;
}
__device__ inline u16 f2bf(float f) {
  __hip_bfloat16 h = __float2bfloat16(f);
  u16 u; __builtin_memcpy(&u, &h, 2); return u;
}
__device__ inline void split3(float x, u16& h, u16& m, u16& l) {
  h = f2bf(x); const float r1 = x - bf2f(h);
  m = f2bf(r1); const float r2 = r1 - bf2f(m);
  l = f2bf(r2);
}
__device__ inline void gl2lds16(const void* g, void* l) {
  __builtin_amdgcn_global_load_lds((const __attribute__((address_space(1))) unsigned int*)g,
                                   (__attribute__((address_space(3))) unsigned int*)l, 16, 0, 0);
}

// ================= bf16x3 (or x1) NT GEMM, 64x64 tile, 4 waves, z-batched ==================
template<int PLANES>
__global__ __launch_bounds__(256) void x3gemm(
    const u16* __restrict__ Ah0, const u16* __restrict__ Am0, const u16* __restrict__ Al0,
    const u16* __restrict__ Ah1, const u16* __restrict__ Am1, const u16* __restrict__ Al1,
    const u16* __restrict__ Bh, const u16* __restrict__ Bm, const u16* __restrict__ Bl,
    const float* __restrict__ bias0, const float* __restrict__ bias1,
    float* __restrict__ C0, float* __restrict__ C1,
    int K, int Nstride, int Mlim, int Nlim)
{
  __shared__ u16 lA[PLANES][64 * 32];
  __shared__ u16 lB[PLANES][64 * 32];
  const int zz = blockIdx.z;
  const u16* Ap[3] = { zz ? Ah1 : Ah0, zz ? Am1 : Am0, zz ? Al1 : Al0 };
  const u16* Bp[3] = {Bh, Bm, Bl};
  const float* bias = zz ? bias1 : bias0;
  float* C = zz ? C1 : C0;
  const int tid = threadIdx.x;
  const int wave = tid >> 6, lane = tid & 63;
  const int wr = wave >> 1, wc = wave & 1;
  const int row0 = blockIdx.y * 64, col0 = blockIdx.x * 64;

  f32x4 acc[2][2];
#pragma unroll
  for (int m = 0; m < 2; ++m)
#pragma unroll
    for (int n = 0; n < 2; ++n) acc[m][n] = (f32x4){0.f, 0.f, 0.f, 0.f};

  const int srow = lane >> 2, sslot = lane & 3;
  const int r15 = lane & 15, kq = lane >> 4;

  for (int k0 = 0; k0 < K; k0 += 32) {
    const int row = wave * 16 + srow;
    const int kg = sslot ^ ((row >> 1) & 3);
#pragma unroll
    for (int p = 0; p < PLANES; ++p) {
      gl2lds16(Ap[p] + (size_t)(row0 + row) * K + k0 + kg * 8, (u16*)lA[p] + wave * 512);
      gl2lds16(Bp[p] + (size_t)(col0 + row) * K + k0 + kg * 8, (u16*)lB[p] + wave * 512);
    }
    __syncthreads();
    short8 a[PLANES][2], b[PLANES][2];
#pragma unroll
    for (int m = 0; m < 2; ++m) {
      const int rowL = wr * 32 + m * 16 + r15;
      const int slot = kq ^ ((rowL >> 1) & 3);
#pragma unroll
      for (int p = 0; p < PLANES; ++p)
        a[p][m] = *reinterpret_cast<const short8*>(&lA[p][rowL * 32 + slot * 8]);
    }
#pragma unroll
    for (int n = 0; n < 2; ++n) {
      const int colL = wc * 32 + n * 16 + r15;
      const int slot = kq ^ ((colL >> 1) & 3);
#pragma unroll
      for (int p = 0; p < PLANES; ++p)
        b[p][n] = *reinterpret_cast<const short8*>(&lB[p][colL * 32 + slot * 8]);
    }
#pragma unroll
    for (int m = 0; m < 2; ++m)
#pragma unroll
      for (int n = 0; n < 2; ++n) {
        if constexpr (PLANES == 3) {
          acc[m][n] = __builtin_amdgcn_mfma_f32_16x16x32_bf16(a[2][m], b[0][n], acc[m][n], 0, 0, 0);
          acc[m][n] = __builtin_amdgcn_mfma_f32_16x16x32_bf16(a[0][m], b[2][n], acc[m][n], 0, 0, 0);
          acc[m][n] = __builtin_amdgcn_mfma_f32_16x16x32_bf16(a[1][m], b[1][n], acc[m][n], 0, 0, 0);
          acc[m][n] = __builtin_amdgcn_mfma_f32_16x16x32_bf16(a[1][m], b[0][n], acc[m][n], 0, 0, 0);
          acc[m][n] = __builtin_amdgcn_mfma_f32_16x16x32_bf16(a[0][m], b[1][n], acc[m][n], 0, 0, 0);
          acc[m][n] = __builtin_amdgcn_mfma_f32_16x16x32_bf16(a[0][m], b[0][n], acc[m][n], 0, 0, 0);
        } else {
          acc[m][n] = __builtin_amdgcn_mfma_f32_16x16x32_bf16(a[0][m], b[0][n], acc[m][n], 0, 0, 0);
        }
      }
    __syncthreads();
  }
  const int quad = lane >> 4;
#pragma unroll
  for (int m = 0; m < 2; ++m)
#pragma unroll
    for (int n = 0; n < 2; ++n) {
      const int cg = col0 + wc * 32 + n * 16 + r15;
      if (cg >= Nlim) continue;
      const float ev = bias ? bias[cg] : 0.f;
#pragma unroll
      for (int reg = 0; reg < 4; ++reg) {
        const int rg = row0 + wr * 32 + m * 16 + quad * 4 + reg;
        if (rg < Mlim) C[(size_t)rg * Nstride + cg] = acc[m][n][reg] + ev;
      }
    }
}

// ============ scores MFMA (128x128, BK=32, XCD-swizzled) ============
// Kt = key((A@B^T + cvec)/32) with mask applied in epilogue; masked/pad -> key 0.
__global__ __launch_bounds__(256) void mfma_scores128(
    const u16* __restrict__ A, const u16* __restrict__ B,
    const float* __restrict__ cvec, const unsigned long long* __restrict__ fbits,
    const unsigned* __restrict__ fij, u16* __restrict__ Kt, int K, int Nlim)
{
  __shared__ u16 ldsA[128 * 32];
  __shared__ u16 ldsB[128 * 32];
  const int tid = threadIdx.x;
  const int wave = tid >> 6, lane = tid & 63;
  const int wr = wave >> 1, wc = wave & 1;
  unsigned wg = blockIdx.y * gridDim.x + blockIdx.x;
  const unsigned per = (gridDim.x * gridDim.y) >> 3;
  wg = (wg & 7) * per + (wg >> 3);
  const int row0 = (int)(wg / gridDim.x) * 128, col0 = (int)(wg % gridDim.x) * 128;

  f32x4 acc[4][4];
#pragma unroll
  for (int m = 0; m < 4; ++m)
#pragma unroll
    for (int n = 0; n < 4; ++n) acc[m][n] = (f32x4){0.f, 0.f, 0.f, 0.f};

  const int srow = lane >> 2, sslot = lane & 3;

  for (int k0 = 0; k0 < K; k0 += 32) {
#pragma unroll
    for (int j = 0; j < 2; ++j) {
      const int row = (wave * 2 + j) * 16 + srow;
      const int kg = sslot ^ ((row >> 1) & 3);
      gl2lds16(A + (size_t)(row0 + row) * K + k0 + kg * 8, (char*)ldsA + (size_t)(wave * 2 + j) * 1024);
      gl2lds16(B + (size_t)(col0 + row) * K + k0 + kg * 8, (char*)ldsB + (size_t)(wave * 2 + j) * 1024);
    }
    __syncthreads();
    const int r15 = lane & 15, kq = lane >> 4;
    short8 a[4], b[4];
#pragma unroll
    for (int m = 0; m < 4; ++m) {
      const int rowL = wr * 64 + m * 16 + r15;
      const int slot = kq ^ ((rowL >> 1) & 3);
      a[m] = *reinterpret_cast<const short8*>(&ldsA[rowL * 32 + slot * 8]);
    }
#pragma unroll
    for (int n = 0; n < 4; ++n) {
      const int colL = wc * 64 + n * 16 + r15;
      const int slot = kq ^ ((colL >> 1) & 3);
      b[n] = *reinterpret_cast<const short8*>(&ldsB[colL * 32 + slot * 8]);
    }
#pragma unroll
    for (int m = 0; m < 4; ++m)
#pragma unroll
      for (int n = 0; n < 4; ++n)
        acc[m][n] = __builtin_amdgcn_mfma_f32_16x16x32_bf16(a[m], b[n], acc[m][n], 0, 0, 0);
    __syncthreads();
  }
  const int r15 = lane & 15, quad = lane >> 4;
#pragma unroll
  for (int m = 0; m < 4; ++m) {
    const int rgb = row0 + wr * 64 + m * 16 + quad * 4;
    unsigned long long fbr[4];
#pragma unroll
    for (int reg = 0; reg < 4; ++reg) fbr[reg] = fbits[rgb + reg];
#pragma unroll
    for (int n = 0; n < 4; ++n) {
      const int cg = col0 + wc * 64 + n * 16 + r15;
      const bool vc = (cg < Nlim);
      const float cv = vc ? cvec[cg] : 0.f;
      const unsigned pp = vc ? fij[cg] : 0u;
      const unsigned fi = pp & 63u, fj = pp >> 16;
#pragma unroll
      for (int reg = 0; reg < 4; ++reg) {
        u16 okey = 0;
        if (vc && ((((fbr[reg] >> fi) & (fbr[reg] >> fj)) & 1ULL) != 0)) {
          const float s = (acc[m][n][reg] + cv) * 0.03125f;
          const u16 u = f2bf(s);
          okey = (u & 0x8000) ? (u16)(~u) : (u16)(u | 0x8000);
        }
        __builtin_nontemporal_store(okey, &Kt[(size_t)(rgb + reg) * NPAD + cg]);
      }
    }
  }
}

// ================= MEGA-PREP: all independent early conversions in one launch =================
// blocks: [0,2048) Wq/Wk T-decomp | [2048,2816) Wt T-decomp | [2816,4352) rel d3 |
// [4352,5376) Wv d3 | [5376,9472) fbits+fij | [9472,9728) u1 | [9728,9984) cvv |
// [9984,14080) qh conv (grid-stride)
__global__ __launch_bounds__(256) void mega_prep(
    const float* __restrict__ Wq, const float* __restrict__ Wk, const float* __restrict__ Wt,
    const float* __restrict__ rel, const float* __restrict__ Wv, const float* __restrict__ qh,
    const void* __restrict__ mask, const int* __restrict__ f_i, const int* __restrict__ f_j,
    const float* __restrict__ bq, const float* __restrict__ bt, const float* __restrict__ bv,
    u16* __restrict__ R1, u16* __restrict__ R2, u16* __restrict__ WtTp,
    u16* __restrict__ relp, u16* __restrict__ R3, u16* __restrict__ qhb,
    unsigned long long* __restrict__ fbits, unsigned* __restrict__ fij,
    float* __restrict__ u1, float* __restrict__ cvv)
{
  __shared__ float t[32][33];
  const int tid = threadIdx.x;
  int b = blockIdx.x;
  const size_t PL1 = (size_t)1024 * 1024;
  const size_t PLW = (size_t)768 * 1024;
  const size_t PLR = (size_t)MPADR * EDIM;

  if (b < 2048) {                       // Wq / Wk transpose-decompose -> R1 / R2
    const float* in = (b < 1024) ? Wq : Wk;
    u16* H = (b < 1024) ? R1 : R2;
    const int bb = b & 1023;
    const int bx = bb & 31, by = bb >> 5;
    const int x = tid & 31, y = tid >> 5;
#pragma unroll
    for (int yy = 0; yy < 4; ++yy)
      t[y + yy * 8][x] = in[(size_t)(by * 32 + y + yy * 8) * 1024 + bx * 32 + x];
    __syncthreads();
#pragma unroll
    for (int yy = 0; yy < 4; ++yy) {
      u16 h, m, l; split3(t[x][y + yy * 8], h, m, l);
      const size_t o = (size_t)(bx * 32 + y + yy * 8) * 1024 + by * 32 + x;
      H[o] = h; H[o + PL1] = m; H[o + 2 * PL1] = l;
    }
    return;
  }
  b -= 2048;
  if (b < 768) {                        // Wt [1024][768] -> WtTp [768][1024] x3
    const int bx = b % 24, by = b / 24;
    const int x = tid & 31, y = tid >> 5;
#pragma unroll
    for (int yy = 0; yy < 4; ++yy)
      t[y + yy * 8][x] = Wt[(size_t)(by * 32 + y + yy * 8) * 768 + bx * 32 + x];
    __syncthreads();
#pragma unroll
    for (int yy = 0; yy < 4; ++yy) {
      u16 h, m, l; split3(t[x][y + yy * 8], h, m, l);
      const size_t o = (size_t)(bx * 32 + y + yy * 8) * 1024 + by * 32 + x;
      WtTp[o] = h; WtTp[o + PLW] = m; WtTp[o + 2 * PLW] = l;
    }
    return;
  }
  b -= 768;
  if (b < 1536) {                       // rel decompose3 -> relp (pad rows zero)
    const long i = (long)b * 256 + tid;
    const long nvalid = (long)R_REL * EDIM / 4;
    u16 oh[4] = {0,0,0,0}, om[4] = {0,0,0,0}, ol[4] = {0,0,0,0};
    if (i < nvalid) {
      const float4 f = *reinterpret_cast<const float4*>(rel + i * 4);
      const float xs[4] = {f.x, f.y, f.z, f.w};
#pragma unroll
      for (int k = 0; k < 4; ++k) split3(xs[k], oh[k], om[k], ol[k]);
    }
    *reinterpret_cast<ulong1*>(relp + i * 4)           = *reinterpret_cast<ulong1*>(oh);
    *reinterpret_cast<ulong1*>(relp + PLR + i * 4)     = *reinterpret_cast<ulong1*>(om);
    *reinterpret_cast<ulong1*>(relp + 2 * PLR + i * 4) = *reinterpret_cast<ulong1*>(ol);
    return;
  }
  b -= 1536;
  if (b < 1024) {                       // Wv decompose3 -> R3 planes
    const long i = (long)b * 256 + tid;
    const float4 f = *reinterpret_cast<const float4*>(Wv + i * 4);
    const float xs[4] = {f.x, f.y, f.z, f.w};
    u16 oh[4], om[4], ol[4];
#pragma unroll
    for (int k = 0; k < 4; ++k) split3(xs[k], oh[k], om[k], ol[k]);
    *reinterpret_cast<ulong1*>(R3 + i * 4)           = *reinterpret_cast<ulong1*>(oh);
    *reinterpret_cast<ulong1*>(R3 + PL1 + i * 4)     = *reinterpret_cast<ulong1*>(om);
    *reinterpret_cast<ulong1*>(R3 + 2 * PL1 + i * 4) = *reinterpret_cast<ulong1*>(ol);
    return;
  }
  b -= 1024;
  if (b < 4096) {                       // fbits (self-detecting kind) + fij
    const int gm = b * 4 + (tid >> 6);
    const int lane = tid & 63;
    const unsigned* mw = (const unsigned*)mask;
    bool sawf = false, sawg = false;
#pragma unroll
    for (int k = 0; k < 4; ++k) {
      const unsigned w = mw[lane * 4 + k];
      sawf |= (w == 0x3F800000u);
      sawg |= (w > 1u);
    }
    const int kind = __ballot(sawf) ? 2 : (__ballot(sawg) ? 1 : 0);
    const size_t e = (size_t)gm * 64 + lane;
    bool on;
    if (kind == 0)      on = ((const int*)mask)[e] != 0;
    else if (kind == 1) on = ((const unsigned char*)mask)[e] != 0;
    else                on = ((const float*)mask)[e] != 0.f;
    const unsigned long long bb = __ballot(on);
    if (lane == 0) fbits[gm] = bb;
    if (b < 8) {
      const int i = b * 256 + tid;
      const int src = (i < R_REL) ? i : (R_REL - 1);
      fij[i] = ((unsigned)f_i[src] & 0xFFFFu) | (((unsigned)f_j[src] & 0xFFFFu) << 16);
    }
    return;
  }
  b -= 4096;
  if (b < 256) {                        // u1 = Wk^T . bq
    const int row = b * 4 + (tid >> 6);
    const int lane = tid & 63;
    float acc = 0.f;
#pragma unroll
    for (int j = 0; j < 16; ++j)
      acc = fmaf(Wk[row + (size_t)(lane + j * 64) * HDIM], bq[lane + j * 64], acc);
#pragma unroll
    for (int off = 32; off; off >>= 1) acc += __shfl_xor(acc, off);
    if (lane == 0) u1[row] = acc;
    return;
  }
  b -= 256;
  if (b < 256) {                        // cvv = Wv . bt + bv
    const int row = b * 4 + (tid >> 6);
    const int lane = tid & 63;
    float acc = 0.f;
#pragma unroll
    for (int j = 0; j < 16; ++j)
      acc = fmaf(Wv[(size_t)row * HDIM + lane + j * 64], bt[lane + j * 64], acc);
#pragma unroll
    for (int off = 32; off; off >>= 1) acc += __shfl_xor(acc, off);
    if (lane == 0) cvv[row] = acc + bv[row];
    return;
  }
  b -= 256;
  {                                     // qh -> qhb bf16, grid-stride over 4096 blocks
    for (long i = (long)b * 256 + tid; i < (long)MROWS * HDIM / 4; i += 4096L * 256) {
      const float4 f = *reinterpret_cast<const float4*>(qh + i * 4);
      u16 o[4] = {f2bf(f.x), f2bf(f.y), f2bf(f.z), f2bf(f.w)};
      *reinterpret_cast<ulong1*>(qhb + i * 4) = *reinterpret_cast<ulong1*>(o);
    }
  }
}

// ================= decompose / conv helpers (critical-path ones kept standalone) ===========
__global__ __launch_bounds__(256) void decompose3(
    const float* __restrict__ in, u16* __restrict__ H, u16* __restrict__ M, u16* __restrict__ L,
    long n4_total, long n4_valid)
{
  for (long i = blockIdx.x * 256 + threadIdx.x; i < n4_total; i += (long)gridDim.x * 256) {
    u16 oh[4] = {0,0,0,0}, om[4] = {0,0,0,0}, ol[4] = {0,0,0,0};
    if (i < n4_valid) {
      const float4 f = *reinterpret_cast<const float4*>(in + i * 4);
      const float xs[4] = {f.x, f.y, f.z, f.w};
#pragma unroll
      for (int k = 0; k < 4; ++k) split3(xs[k], oh[k], om[k], ol[k]);
    }
    *reinterpret_cast<ulong1*>(H + i * 4) = *reinterpret_cast<ulong1*>(oh);
    *reinterpret_cast<ulong1*>(M + i * 4) = *reinterpret_cast<ulong1*>(om);
    *reinterpret_cast<ulong1*>(L + i * 4) = *reinterpret_cast<ulong1*>(ol);
  }
}

__global__ __launch_bounds__(256) void conv2seg(
    const float* __restrict__ inA, u16* __restrict__ outA, long nb_a, long n4a_valid,
    const float* __restrict__ inB, u16* __restrict__ outB)
{
  const long b = blockIdx.x;
  const float* in; u16* out; long i;
  bool valid = true;
  if (b < nb_a) { in = inA; out = outA; i = b * 256 + threadIdx.x; valid = (i < n4a_valid); }
  else          { in = inB; out = outB; i = (b - nb_a) * 256 + threadIdx.x; }
  u16 o[4] = {0, 0, 0, 0};
  if (valid) {
    const float4 f = *reinterpret_cast<const float4*>(in + i * 4);
    o[0] = f2bf(f.x); o[1] = f2bf(f.y); o[2] = f2bf(f.z); o[3] = f2bf(f.w);
  }
  *reinterpret_cast<ulong1*>(out + i * 4) = *reinterpret_cast<ulong1*>(o);
}

// ================= bias-vector chain (dependent, tiny) =================
__global__ __launch_bounds__(256) void u2_k(
    const float* __restrict__ Wt, const float* __restrict__ u1, float* __restrict__ u2)
{
  const int row = blockIdx.x * 4 + (threadIdx.x >> 6);
  const int lane = threadIdx.x & 63;
  float acc = 0.f;
#pragma unroll
  for (int j = 0; j < 16; ++j)
    acc = fmaf(Wt[row + (size_t)(lane + j * 64) * EDIM], u1[lane + j * 64], acc);
#pragma unroll
  for (int off = 32; off; off >>= 1) acc += __shfl_xor(acc, off);
  if (lane == 0) u2[row] = acc;
}

__global__ __launch_bounds__(256) void cvec_k(
    const float* __restrict__ rel, const float* __restrict__ u2,
    const float* __restrict__ u1, const float* __restrict__ bt,
    const float* __restrict__ bk, const float* __restrict__ bq, float* __restrict__ cvec)
{
  const int row = blockIdx.x * 4 + (threadIdx.x >> 6);
  const int lane = threadIdx.x & 63;
  if (row >= R_REL) return;
  float acc = 0.f;
#pragma unroll
  for (int j = 0; j < 12; ++j)
    acc = fmaf(rel[(size_t)row * EDIM + lane + j * 64], u2[lane + j * 64], acc);
  float sac = 0.f;
#pragma unroll
  for (int j = 0; j < 16; ++j) {
    const int k = lane + j * 64;
    sac = fmaf(bt[k], u1[k], sac);
    sac = fmaf(bk[k], bq[k], sac);
  }
  acc += sac;
#pragma unroll
  for (int off = 32; off; off >>= 1) acc += __shfl_xor(acc, off);
  if (lane == 0) cvec[row] = acc;
}

__global__ __launch_bounds__(256) void w2bias_k(
    const float* __restrict__ T1f, const float* __restrict__ Wq,
    const float* __restrict__ bt, const float* __restrict__ bk, float* __restrict__ w2bias)
{
  const int row = blockIdx.x * 4 + (threadIdx.x >> 6);
  const int lane = threadIdx.x & 63;
  float acc = 0.f;
#pragma unroll
  for (int j = 0; j < 16; ++j) {
    const int k = lane + j * 64;
    acc = fmaf(T1f[(size_t)row * HDIM + k], bt[k], acc);
    acc = fmaf(Wq[row + (size_t)k * HDIM], bk[k], acc);
  }
#pragma unroll
  for (int off = 32; off; off >>= 1) acc += __shfl_xor(acc, off);
  if (lane == 0) w2bias[row] = acc;
}

// ====== PHASE A: pure-stream radix prefilter -> zero-padded candidate lists ======
__global__ __launch_bounds__(64) void prefilter_k(
    const u16* __restrict__ Kt, u16* __restrict__ candidx, int* __restrict__ ncands)
{
  const int gm = blockIdx.x;
  const int lane = threadIdx.x;
  unsigned key[32];
  const u16* rowp = Kt + (size_t)gm * NPAD;
#pragma unroll
  for (int L = 0; L < 4; ++L) {
    const short8 v = *reinterpret_cast<const short8*>(rowp + lane * 8 + L * 512);
#pragma unroll
    for (int r = 0; r < 8; ++r) key[L * 8 + r] = (unsigned)(u16)v[r];
  }
  int lo = 1, hi = 65536;
  while (hi - lo > 1) {
    const int mid = (lo + hi) >> 1;
    int cnt = 0;
#pragma unroll
    for (int j = 0; j < 32; ++j)
      cnt += __popcll(__ballot(key[j] >= (unsigned)mid));
    if (cnt >= KSEL) lo = mid; else hi = mid;
  }
  const unsigned T = (unsigned)lo;
  int base = 0;
#pragma unroll
  for (int L = 0; L < 4; ++L) {
#pragma unroll
    for (int r = 0; r < 8; ++r) {
      const int j = L * 8 + r;
      const bool c = key[j] >= T;
      const unsigned long long m = __ballot(c);
      const int pre = __builtin_amdgcn_mbcnt_hi((unsigned)(m >> 32),
                      __builtin_amdgcn_mbcnt_lo((unsigned)m, 0));
      const int slot = base + pre;
      if (c && slot < CAP) candidx[(size_t)gm * CAP + slot] = (u16)(lane * 8 + r + L * 512);
      base += __popcll(m);
    }
  }
  const int nc = (base < CAP) ? base : CAP;
  for (int s = nc + lane; s < CAP; s += 64) candidx[(size_t)gm * CAP + s] = 0;
  if (lane == 0) ncands[gm] = nc;
}

// ====== PHASE B: exact f32 rescore (fixed-trip, 2-way interleaved) + top-28 + softmax ======
__global__ __launch_bounds__(64) void rescore_k(
    const u16* __restrict__ candidx, const int* __restrict__ ncands,
    const float* __restrict__ qh, const float* __restrict__ W2, const float* __restrict__ cvec,
    int* __restrict__ topidx, float* __restrict__ topw)
{
  const int gm = blockIdx.x;
  const int lane = threadIdx.x;
  const int ncand = ncands[gm];
  const int cslot = (lane < CAP) ? (int)candidx[(size_t)gm * CAP + lane] : 0;

  float q[16];
  {
    const float* qp = qh + (size_t)gm * HDIM + lane * 16;
#pragma unroll
    for (int v4 = 0; v4 < 4; ++v4) {
      const f32x4 f = __builtin_nontemporal_load(reinterpret_cast<const f32x4*>(qp + v4 * 4));
      q[v4 * 4 + 0] = f.x; q[v4 * 4 + 1] = f.y; q[v4 * 4 + 2] = f.z; q[v4 * 4 + 3] = f.w;
    }
  }

  float myscore = -INFINITY;
  for (int c = 0; c < CAP; c += 2) {
    const int ra = __shfl(cslot, c);
    const int rb = __shfl(cslot, c + 1);
    const float* wa = W2 + (size_t)ra * HDIM + lane * 16;
    const float* wb = W2 + (size_t)rb * HDIM + lane * 16;
    const f32x4 a0 = *reinterpret_cast<const f32x4*>(wa);
    const f32x4 b0 = *reinterpret_cast<const f32x4*>(wb);
    const f32x4 a1 = *reinterpret_cast<const f32x4*>(wa + 4);
    const f32x4 b1 = *reinterpret_cast<const f32x4*>(wb + 4);
    const f32x4 a2 = *reinterpret_cast<const f32x4*>(wa + 8);
    const f32x4 b2 = *reinterpret_cast<const f32x4*>(wb + 8);
    const f32x4 a3 = *reinterpret_cast<const f32x4*>(wa + 12);
    const f32x4 b3 = *reinterpret_cast<const f32x4*>(wb + 12);
    float da = 0.f, db = 0.f;
    da = fmaf(q[0],  a0.x, da); db = fmaf(q[0],  b0.x, db);
    da = fmaf(q[1],  a0.y, da); db = fmaf(q[1],  b0.y, db);
    da = fmaf(q[2],  a0.z, da); db = fmaf(q[2],  b0.z, db);
    da = fmaf(q[3],  a0.w, da); db = fmaf(q[3],  b0.w, db);
    da = fmaf(q[4],  a1.x, da); db = fmaf(q[4],  b1.x, db);
    da = fmaf(q[5],  a1.y, da); db = fmaf(q[5],  b1.y, db);
    da = fmaf(q[6],  a1.z, da); db = fmaf(q[6],  b1.z, db);
    da = fmaf(q[7],  a1.w, da); db = fmaf(q[7],  b1.w, db);
    da = fmaf(q[8],  a2.x, da); db = fmaf(q[8],  b2.x, db);
    da = fmaf(q[9],  a2.y, da); db = fmaf(q[9],  b2.y, db);
    da = fmaf(q[10], a2.z, da); db = fmaf(q[10], b2.z, db);
    da = fmaf(q[11], a2.w, da); db = fmaf(q[11], b2.w, db);
    da = fmaf(q[12], a3.x, da); db = fmaf(q[12], b3.x, db);
    da = fmaf(q[13], a3.y, da); db = fmaf(q[13], b3.y, db);
    da = fmaf(q[14], a3.z, da); db = fmaf(q[14], b3.z, db);
    da = fmaf(q[15], a3.w, da); db = fmaf(q[15], b3.w, db);
#pragma unroll
    for (int off = 32; off; off >>= 1) {
      da += __shfl_xor(da, off);
      db += __shfl_xor(db, off);
    }
    if (lane == c)     myscore = (da + cvec[ra]) * 0.03125f;
    if (lane == c + 1) myscore = (db + cvec[rb]) * 0.03125f;
  }
  int myr = 0x7fffffff;
  if (lane < ncand) myr = cslot;
  else myscore = -INFINITY;

  // bitonic sort 64 lanes, descending score, tie -> ascending index
#pragma unroll
  for (int k = 2; k <= 64; k <<= 1) {
#pragma unroll
    for (int j = k >> 1; j > 0; j >>= 1) {
      const float ov = __shfl_xor(myscore, j);
      const int oi = __shfl_xor(myr, j);
      const bool lower = (lane & j) == 0;
      const bool want_desc = (lane & k) == 0;
      const bool mine_better = (myscore > ov) || (myscore == ov && myr < oi);
      const bool keep = (lower == want_desc) ? mine_better : !mine_better;
      if (!keep) { myscore = ov; myr = oi; }
    }
  }

  const int nvalid = __popcll(__ballot(myscore > -INFINITY));
  const int nsel = (nvalid < TOPK) ? nvalid : TOPK;
  const float m0 = __shfl(myscore, 0);
  const float e = (lane < nsel) ? expf(myscore - m0) : 0.f;
  float z = e;
#pragma unroll
  for (int off = 32; off; off >>= 1) z += __shfl_xor(z, off);
  if (lane < TOPK) {
    topw[(size_t)gm * TOPK + lane] = (lane < nsel) ? (e / z) : 0.f;
    topidx[(size_t)gm * TOPK + lane] = (lane < nsel) ? myr : 0;
  }
}

// ====== PHASE C: sparse V-gather ======
__global__ __launch_bounds__(256) void out_gather(
    const int* __restrict__ topidx, const float* __restrict__ topw,
    const float* __restrict__ V, float* __restrict__ out)
{
  const int gm = blockIdx.x;
  const int tid = threadIdx.x;
  __shared__ float w[TOPK];
  __shared__ int   id[TOPK];
  if (tid < TOPK) {
    w[tid] = topw[(size_t)gm * TOPK + tid];
    id[tid] = topidx[(size_t)gm * TOPK + tid];
  }
  __syncthreads();
  float4 acc = make_float4(0.f, 0.f, 0.f, 0.f);
#pragma unroll 4
  for (int i = 0; i < TOPK; ++i) {
    const float wi = w[i];
    const float4 v = *reinterpret_cast<const float4*>(V + (size_t)id[i] * HDIM + tid * 4);
    acc.x = fmaf(wi, v.x, acc.x);
    acc.y = fmaf(wi, v.y, acc.y);
    acc.z = fmaf(wi, v.z, acc.z);
    acc.w = fmaf(wi, v.w, acc.w);
  }
  *reinterpret_cast<float4*>(out + (size_t)gm * HDIM + tid * 4) = acc;
}

extern "C" void kernel_launch(void* const* d_in, const int* in_sizes, int n_in,
                              void* d_out, int out_size, void* d_ws, size_t ws_size,
                              hipStream_t stream) {
  const float* qh  = (const float*)d_in[0];
  const void*  mask = d_in[1];
  const float* rel = (const float*)d_in[2];
  const int* f_i = (const int*)d_in[3];
  const int* f_j = (const int*)d_in[4];
  const float* Wt = (const float*)d_in[5]; const float* bt = (const float*)d_in[6];
  const float* Wq = (const float*)d_in[7]; const float* bq = (const float*)d_in[8];
  const float* Wk = (const float*)d_in[9]; const float* bk = (const float*)d_in[10];
  const float* Wv = (const float*)d_in[11]; const float* bv = (const float*)d_in[12];
  float* out = (float*)d_out;

  // ---- workspace layout with lifetime-based aliasing ----
  char* p = (char*)d_ws;
  auto alloc = [&](size_t bytes) { char* q_ = p; p += (bytes + 255) & ~(size_t)255; return q_; };
  float* W2   = (float*)alloc((size_t)R_REL * HDIM * 4);
  char* strip = alloc((size_t)(1024*1024 + 1024*768 + 1024*768) * 4);
  float* T1f = (float*)strip;
  float* Pf  = T1f + 1024 * 1024;
  float* Pvf = Pf + 1024 * 768;
  float* Vm  = (float*)strip;                   // alias (written after T1f/Pf/Pvf dead)
  u16* R1 = (u16*)alloc((size_t)3 * 1024 * 1024 * 2);   // WqT planes -> T1 planes
  u16* R2 = (u16*)alloc((size_t)3 * 1024 * 1024 * 2);   // WkT planes -> P planes
  u16* WtTp = (u16*)alloc((size_t)3 * 768 * 1024 * 2);
  u16* relp = (u16*)alloc((size_t)3 * MPADR * EDIM * 2);
  u16* qhb  = (u16*)alloc((size_t)MROWS * HDIM * 2);
  char* w2b_region = alloc((size_t)NPAD * HDIM * 2);
  u16* W2b  = (u16*)w2b_region;
  u16* Pv16 = (u16*)alloc((size_t)1024 * 768 * 2);
  u16* Kt   = (u16*)alloc((size_t)MROWS * NPAD * 2);
  u16* R3   = Kt;                               // Wv planes (dead before Kt written)
  u16* candidx = (u16*)alloc((size_t)MROWS * CAP * 2);
  int* ncands  = (int*)alloc((size_t)MROWS * 4);
  float* cvec   = (float*)alloc(NPAD * 4);
  float* u1     = (float*)alloc(1024 * 4);
  float* u2     = (float*)alloc(1024 * 4);
  float* w2bias = (float*)alloc(1024 * 4);
  float* cvv    = (float*)alloc(1024 * 4);
  unsigned long long* fbits = (unsigned long long*)alloc((size_t)MROWS * 8);
  unsigned* fij = (unsigned*)alloc(NPAD * 4);
  int* tidx = (int*)w2b_region;                 // alias (W2b dead after scores)
  float* tw = (float*)(w2b_region + (size_t)MROWS * TOPK * 4);

  const size_t PL1 = (size_t)1024 * 1024;
  const size_t PLW = (size_t)768 * 1024;
  const size_t PLR = (size_t)MPADR * EDIM;
  const size_t PLP = (size_t)1024 * 768;

  const dim3 blk(256);

  // 1: all independent early work in one launch
  mega_prep<<<dim3(14080), blk, 0, stream>>>(
      Wq, Wk, Wt, rel, Wv, qh, mask, f_i, f_j, bq, bt, bv,
      R1, R2, WtTp, relp, R3, qhb, fbits, fij, u1, cvv);

  // 2-3: dependent bias chain
  u2_k<<<dim3(192), blk, 0, stream>>>(Wt, u1, u2);
  cvec_k<<<dim3((R_REL + 3) / 4), blk, 0, stream>>>(rel, u2, u1, bt, bk, bq, cvec);

  // 4: T1 = Wq^T @ Wk  (bf16x3)
  x3gemm<3><<<dim3(1024/64, 1024/64, 1), blk, 0, stream>>>(
      R1, R1+PL1, R1+2*PL1, nullptr, nullptr, nullptr,
      R2, R2+PL1, R2+2*PL1, nullptr, nullptr, T1f, nullptr, 1024, 1024, 1024, 1024);
  // 5-6
  w2bias_k<<<dim3(256), blk, 0, stream>>>(T1f, Wq, bt, bk, w2bias);
  decompose3<<<dim3(1024), blk, 0, stream>>>(T1f, R1, R1+PL1, R1+2*PL1, (long)PL1/4, (long)PL1/4);
  // 7: P = T1 @ Wt  and  Pv = Wv @ Wt  (z-batched, shared B = WtT planes)
  x3gemm<3><<<dim3(768/64, 1024/64, 2), blk, 0, stream>>>(
      R1, R1+PL1, R1+2*PL1, R3, R3+PL1, R3+2*PL1,
      WtTp, WtTp+PLW, WtTp+2*PLW, nullptr, nullptr, Pf, Pvf, 1024, 768, 1024, 768);
  // 8
  decompose3<<<dim3(768), blk, 0, stream>>>(Pf, R2, R2+PLP, R2+2*PLP, (long)PLP/4, (long)PLP/4);
  // 9: W2 = rel @ P^T + w2bias
  x3gemm<3><<<dim3(1024/64, MPADR/64, 1), blk, 0, stream>>>(
      relp, relp+PLR, relp+2*PLR, nullptr, nullptr, nullptr,
      R2, R2+PLP, R2+2*PLP, w2bias, nullptr, W2, nullptr, EDIM, HDIM, R_REL, HDIM);

  // 10: W2b (padded) + Pv16 conversions in one launch
  conv2seg<<<dim3(2048 + 768), blk, 0, stream>>>(
      W2, W2b, 2048, (long)R_REL*HDIM/4, Pvf, Pv16);

  // 11: Vm = rel_h @ Pv16^T + cvv  (bf16; aliases the dead f32 strip)
  x3gemm<1><<<dim3(1024/64, MPADR/64, 1), blk, 0, stream>>>(
      relp, nullptr, nullptr, nullptr, nullptr, nullptr,
      Pv16, nullptr, nullptr, cvv, nullptr, Vm, nullptr, EDIM, HDIM, R_REL, HDIM);

  // 12: approx score keys, masked in epilogue (overwrites R3 region — Wv planes dead)
  mfma_scores128<<<dim3(NPAD/128, MROWS/128), blk, 0, stream>>>(
      qhb, W2b, cvec, fbits, fij, Kt, HDIM, R_REL);

  // 13-15: prefilter -> rescore -> gather
  prefilter_k<<<dim3(MROWS), dim3(64), 0, stream>>>(Kt, candidx, ncands);
  rescore_k<<<dim3(MROWS), dim3(64), 0, stream>>>(candidx, ncands, qh, W2, cvec, tidx, tw);
  out_gather<<<dim3(MROWS), blk, 0, stream>>>(tidx, tw, Vm, out);
}

// Round 10
// 638.569 us; speedup vs baseline: 1.1015x; 1.1015x over previous
//
#include <hip/hip_runtime.h>
#include <hip/hip_bf16.h>

#define R_REL 2016
#define MROWS 16384
#define HDIM  1024
#define EDIM  768
#define TOPK  28
#define KSEL  31
#define CAP   48
#define NPAD  2048
#define MPADR 2048

typedef unsigned short u16;
typedef __attribute__((ext_vector_type(8))) short short8;
typedef __attribute__((ext_vector_type(4))) float f32x4;

__device__ inline float bf2f(u16 u) {
  unsigned x = ((unsigned)u) << 16; float f;
  __builtin_memcpy(&f, &x, 4); return f;
}
__device__ inline u16 f2bf(float f) {
  __hip_bfloat16 h = __float2bfloat16(f);
  u16 u; __builtin_memcpy(&u, &h, 2); return u;
}
__device__ inline void split3(float x, u16& h, u16& m, u16& l) {
  h = f2bf(x); const float r1 = x - bf2f(h);
  m = f2bf(r1); const float r2 = r1 - bf2f(m);
  l = f2bf(r2);
}
__device__ inline void gl2lds16(const void* g, void* l) {
  __builtin_amdgcn_global_load_lds((const __attribute__((address_space(1))) unsigned int*)g,
                                   (__attribute__((address_space(3))) unsigned int*)l, 16, 0, 0);
}

// ================= bf16x3 (or x1) NT GEMM, 64x64 tile, 4 waves, z-batched ==================
template<int PLANES>
__global__ __launch_bounds__(256) void x3gemm(
    const u16* __restrict__ Ah0, const u16* __restrict__ Am0, const u16* __restrict__ Al0,
    const u16* __restrict__ Ah1, const u16* __restrict__ Am1, const u16* __restrict__ Al1,
    const u16* __restrict__ Bh, const u16* __restrict__ Bm, const u16* __restrict__ Bl,
    const float* __restrict__ bias0, const float* __restrict__ bias1,
    float* __restrict__ C0, float* __restrict__ C1,
    int K, int Nstride, int Mlim, int Nlim)
{
  __shared__ u16 lA[PLANES][64 * 32];
  __shared__ u16 lB[PLANES][64 * 32];
  const int zz = blockIdx.z;
  const u16* Ap[3] = { zz ? Ah1 : Ah0, zz ? Am1 : Am0, zz ? Al1 : Al0 };
  const u16* Bp[3] = {Bh, Bm, Bl};
  const float* bias = zz ? bias1 : bias0;
  float* C = zz ? C1 : C0;
  const int tid = threadIdx.x;
  const int wave = tid >> 6, lane = tid & 63;
  const int wr = wave >> 1, wc = wave & 1;
  const int row0 = blockIdx.y * 64, col0 = blockIdx.x * 64;

  f32x4 acc[2][2];
#pragma unroll
  for (int m = 0; m < 2; ++m)
#pragma unroll
    for (int n = 0; n < 2; ++n) acc[m][n] = (f32x4){0.f, 0.f, 0.f, 0.f};

  const int srow = lane >> 2, sslot = lane & 3;
  const int r15 = lane & 15, kq = lane >> 4;

  for (int k0 = 0; k0 < K; k0 += 32) {
    const int row = wave * 16 + srow;
    const int kg = sslot ^ ((row >> 1) & 3);
#pragma unroll
    for (int p = 0; p < PLANES; ++p) {
      gl2lds16(Ap[p] + (size_t)(row0 + row) * K + k0 + kg * 8, (u16*)lA[p] + wave * 512);
      gl2lds16(Bp[p] + (size_t)(col0 + row) * K + k0 + kg * 8, (u16*)lB[p] + wave * 512);
    }
    __syncthreads();
    short8 a[PLANES][2], b[PLANES][2];
#pragma unroll
    for (int m = 0; m < 2; ++m) {
      const int rowL = wr * 32 + m * 16 + r15;
      const int slot = kq ^ ((rowL >> 1) & 3);
#pragma unroll
      for (int p = 0; p < PLANES; ++p)
        a[p][m] = *reinterpret_cast<const short8*>(&lA[p][rowL * 32 + slot * 8]);
    }
#pragma unroll
    for (int n = 0; n < 2; ++n) {
      const int colL = wc * 32 + n * 16 + r15;
      const int slot = kq ^ ((colL >> 1) & 3);
#pragma unroll
      for (int p = 0; p < PLANES; ++p)
        b[p][n] = *reinterpret_cast<const short8*>(&lB[p][colL * 32 + slot * 8]);
    }
#pragma unroll
    for (int m = 0; m < 2; ++m)
#pragma unroll
      for (int n = 0; n < 2; ++n) {
        if constexpr (PLANES == 3) {
          acc[m][n] = __builtin_amdgcn_mfma_f32_16x16x32_bf16(a[2][m], b[0][n], acc[m][n], 0, 0, 0);
          acc[m][n] = __builtin_amdgcn_mfma_f32_16x16x32_bf16(a[0][m], b[2][n], acc[m][n], 0, 0, 0);
          acc[m][n] = __builtin_amdgcn_mfma_f32_16x16x32_bf16(a[1][m], b[1][n], acc[m][n], 0, 0, 0);
          acc[m][n] = __builtin_amdgcn_mfma_f32_16x16x32_bf16(a[1][m], b[0][n], acc[m][n], 0, 0, 0);
          acc[m][n] = __builtin_amdgcn_mfma_f32_16x16x32_bf16(a[0][m], b[1][n], acc[m][n], 0, 0, 0);
          acc[m][n] = __builtin_amdgcn_mfma_f32_16x16x32_bf16(a[0][m], b[0][n], acc[m][n], 0, 0, 0);
        } else {
          acc[m][n] = __builtin_amdgcn_mfma_f32_16x16x32_bf16(a[0][m], b[0][n], acc[m][n], 0, 0, 0);
        }
      }
    __syncthreads();
  }
  const int quad = lane >> 4;
#pragma unroll
  for (int m = 0; m < 2; ++m)
#pragma unroll
    for (int n = 0; n < 2; ++n) {
      const int cg = col0 + wc * 32 + n * 16 + r15;
      if (cg >= Nlim) continue;
      const float ev = bias ? bias[cg] : 0.f;
#pragma unroll
      for (int reg = 0; reg < 4; ++reg) {
        const int rg = row0 + wr * 32 + m * 16 + quad * 4 + reg;
        if (rg < Mlim) C[(size_t)rg * Nstride + cg] = acc[m][n][reg] + ev;
      }
    }
}

// ============ scores MFMA (128x128, BK=32, XCD-swizzled) ============
// Kt = key((A@B^T + cvec)/32) with mask applied in epilogue; masked/pad -> key 0.
__global__ __launch_bounds__(256) void mfma_scores128(
    const u16* __restrict__ A, const u16* __restrict__ B,
    const float* __restrict__ cvec, const unsigned long long* __restrict__ fbits,
    const unsigned* __restrict__ fij, u16* __restrict__ Kt, int K, int Nlim)
{
  __shared__ u16 ldsA[128 * 32];
  __shared__ u16 ldsB[128 * 32];
  const int tid = threadIdx.x;
  const int wave = tid >> 6, lane = tid & 63;
  const int wr = wave >> 1, wc = wave & 1;
  unsigned wg = blockIdx.y * gridDim.x + blockIdx.x;
  const unsigned per = (gridDim.x * gridDim.y) >> 3;
  wg = (wg & 7) * per + (wg >> 3);
  const int row0 = (int)(wg / gridDim.x) * 128, col0 = (int)(wg % gridDim.x) * 128;

  f32x4 acc[4][4];
#pragma unroll
  for (int m = 0; m < 4; ++m)
#pragma unroll
    for (int n = 0; n < 4; ++n) acc[m][n] = (f32x4){0.f, 0.f, 0.f, 0.f};

  const int srow = lane >> 2, sslot = lane & 3;

  for (int k0 = 0; k0 < K; k0 += 32) {
#pragma unroll
    for (int j = 0; j < 2; ++j) {
      const int row = (wave * 2 + j) * 16 + srow;
      const int kg = sslot ^ ((row >> 1) & 3);
      gl2lds16(A + (size_t)(row0 + row) * K + k0 + kg * 8, (char*)ldsA + (size_t)(wave * 2 + j) * 1024);
      gl2lds16(B + (size_t)(col0 + row) * K + k0 + kg * 8, (char*)ldsB + (size_t)(wave * 2 + j) * 1024);
    }
    __syncthreads();
    const int r15 = lane & 15, kq = lane >> 4;
    short8 a[4], b[4];
#pragma unroll
    for (int m = 0; m < 4; ++m) {
      const int rowL = wr * 64 + m * 16 + r15;
      const int slot = kq ^ ((rowL >> 1) & 3);
      a[m] = *reinterpret_cast<const short8*>(&ldsA[rowL * 32 + slot * 8]);
    }
#pragma unroll
    for (int n = 0; n < 4; ++n) {
      const int colL = wc * 64 + n * 16 + r15;
      const int slot = kq ^ ((colL >> 1) & 3);
      b[n] = *reinterpret_cast<const short8*>(&ldsB[colL * 32 + slot * 8]);
    }
#pragma unroll
    for (int m = 0; m < 4; ++m)
#pragma unroll
      for (int n = 0; n < 4; ++n)
        acc[m][n] = __builtin_amdgcn_mfma_f32_16x16x32_bf16(a[m], b[n], acc[m][n], 0, 0, 0);
    __syncthreads();
  }
  const int r15 = lane & 15, quad = lane >> 4;
#pragma unroll
  for (int m = 0; m < 4; ++m) {
    const int rgb = row0 + wr * 64 + m * 16 + quad * 4;
    unsigned long long fbr[4];
#pragma unroll
    for (int reg = 0; reg < 4; ++reg) fbr[reg] = fbits[rgb + reg];
#pragma unroll
    for (int n = 0; n < 4; ++n) {
      const int cg = col0 + wc * 64 + n * 16 + r15;
      const bool vc = (cg < Nlim);
      const float cv = vc ? cvec[cg] : 0.f;
      const unsigned pp = vc ? fij[cg] : 0u;
      const unsigned fi = pp & 63u, fj = pp >> 16;
#pragma unroll
      for (int reg = 0; reg < 4; ++reg) {
        u16 okey = 0;
        if (vc && ((((fbr[reg] >> fi) & (fbr[reg] >> fj)) & 1ULL) != 0)) {
          const float s = (acc[m][n][reg] + cv) * 0.03125f;
          const u16 u = f2bf(s);
          okey = (u & 0x8000) ? (u16)(~u) : (u16)(u | 0x8000);
        }
        __builtin_nontemporal_store(okey, &Kt[(size_t)(rgb + reg) * NPAD + cg]);
      }
    }
  }
}

// ================= MEGA-PREP: all independent early conversions in one launch =================
__global__ __launch_bounds__(256) void mega_prep(
    const float* __restrict__ Wq, const float* __restrict__ Wk, const float* __restrict__ Wt,
    const float* __restrict__ rel, const float* __restrict__ Wv, const float* __restrict__ qh,
    const void* __restrict__ mask, const int* __restrict__ f_i, const int* __restrict__ f_j,
    const float* __restrict__ bq, const float* __restrict__ bt, const float* __restrict__ bv,
    u16* __restrict__ R1, u16* __restrict__ R2, u16* __restrict__ WtTp,
    u16* __restrict__ relp, u16* __restrict__ R3, u16* __restrict__ qhb,
    unsigned long long* __restrict__ fbits, unsigned* __restrict__ fij,
    float* __restrict__ u1, float* __restrict__ cvv)
{
  __shared__ float t[32][33];
  const int tid = threadIdx.x;
  int b = blockIdx.x;
  const size_t PL1 = (size_t)1024 * 1024;
  const size_t PLW = (size_t)768 * 1024;
  const size_t PLR = (size_t)MPADR * EDIM;

  if (b < 2048) {                       // Wq / Wk transpose-decompose -> R1 / R2
    const float* in = (b < 1024) ? Wq : Wk;
    u16* H = (b < 1024) ? R1 : R2;
    const int bb = b & 1023;
    const int bx = bb & 31, by = bb >> 5;
    const int x = tid & 31, y = tid >> 5;
#pragma unroll
    for (int yy = 0; yy < 4; ++yy)
      t[y + yy * 8][x] = in[(size_t)(by * 32 + y + yy * 8) * 1024 + bx * 32 + x];
    __syncthreads();
#pragma unroll
    for (int yy = 0; yy < 4; ++yy) {
      u16 h, m, l; split3(t[x][y + yy * 8], h, m, l);
      const size_t o = (size_t)(bx * 32 + y + yy * 8) * 1024 + by * 32 + x;
      H[o] = h; H[o + PL1] = m; H[o + 2 * PL1] = l;
    }
    return;
  }
  b -= 2048;
  if (b < 768) {                        // Wt [1024][768] -> WtTp [768][1024] x3
    const int bx = b % 24, by = b / 24;
    const int x = tid & 31, y = tid >> 5;
#pragma unroll
    for (int yy = 0; yy < 4; ++yy)
      t[y + yy * 8][x] = Wt[(size_t)(by * 32 + y + yy * 8) * 768 + bx * 32 + x];
    __syncthreads();
#pragma unroll
    for (int yy = 0; yy < 4; ++yy) {
      u16 h, m, l; split3(t[x][y + yy * 8], h, m, l);
      const size_t o = (size_t)(bx * 32 + y + yy * 8) * 1024 + by * 32 + x;
      WtTp[o] = h; WtTp[o + PLW] = m; WtTp[o + 2 * PLW] = l;
    }
    return;
  }
  b -= 768;
  if (b < 1536) {                       // rel decompose3 -> relp (pad rows zero)
    const long i = (long)b * 256 + tid;
    const long nvalid = (long)R_REL * EDIM / 4;
    u16 oh[4] = {0,0,0,0}, om[4] = {0,0,0,0}, ol[4] = {0,0,0,0};
    if (i < nvalid) {
      const float4 f = *reinterpret_cast<const float4*>(rel + i * 4);
      const float xs[4] = {f.x, f.y, f.z, f.w};
#pragma unroll
      for (int k = 0; k < 4; ++k) split3(xs[k], oh[k], om[k], ol[k]);
    }
    *reinterpret_cast<ulong1*>(relp + i * 4)           = *reinterpret_cast<ulong1*>(oh);
    *reinterpret_cast<ulong1*>(relp + PLR + i * 4)     = *reinterpret_cast<ulong1*>(om);
    *reinterpret_cast<ulong1*>(relp + 2 * PLR + i * 4) = *reinterpret_cast<ulong1*>(ol);
    return;
  }
  b -= 1536;
  if (b < 1024) {                       // Wv decompose3 -> R3 planes
    const long i = (long)b * 256 + tid;
    const float4 f = *reinterpret_cast<const float4*>(Wv + i * 4);
    const float xs[4] = {f.x, f.y, f.z, f.w};
    u16 oh[4], om[4], ol[4];
#pragma unroll
    for (int k = 0; k < 4; ++k) split3(xs[k], oh[k], om[k], ol[k]);
    *reinterpret_cast<ulong1*>(R3 + i * 4)           = *reinterpret_cast<ulong1*>(oh);
    *reinterpret_cast<ulong1*>(R3 + PL1 + i * 4)     = *reinterpret_cast<ulong1*>(om);
    *reinterpret_cast<ulong1*>(R3 + 2 * PL1 + i * 4) = *reinterpret_cast<ulong1*>(ol);
    return;
  }
  b -= 1024;
  if (b < 4096) {                       // fbits (self-detecting kind) + fij
    const int gm = b * 4 + (tid >> 6);
    const int lane = tid & 63;
    const unsigned* mw = (const unsigned*)mask;
    bool sawf = false, sawg = false;
#pragma unroll
    for (int k = 0; k < 4; ++k) {
      const unsigned w = mw[lane * 4 + k];
      sawf |= (w == 0x3F800000u);
      sawg |= (w > 1u);
    }
    const int kind = __ballot(sawf) ? 2 : (__ballot(sawg) ? 1 : 0);
    const size_t e = (size_t)gm * 64 + lane;
    bool on;
    if (kind == 0)      on = ((const int*)mask)[e] != 0;
    else if (kind == 1) on = ((const unsigned char*)mask)[e] != 0;
    else                on = ((const float*)mask)[e] != 0.f;
    const unsigned long long bb = __ballot(on);
    if (lane == 0) fbits[gm] = bb;
    if (b < 8) {
      const int i = b * 256 + tid;
      const int src = (i < R_REL) ? i : (R_REL - 1);
      fij[i] = ((unsigned)f_i[src] & 0xFFFFu) | (((unsigned)f_j[src] & 0xFFFFu) << 16);
    }
    return;
  }
  b -= 4096;
  if (b < 256) {                        // u1 = Wk^T . bq
    const int row = b * 4 + (tid >> 6);
    const int lane = tid & 63;
    float acc = 0.f;
#pragma unroll
    for (int j = 0; j < 16; ++j)
      acc = fmaf(Wk[row + (size_t)(lane + j * 64) * HDIM], bq[lane + j * 64], acc);
#pragma unroll
    for (int off = 32; off; off >>= 1) acc += __shfl_xor(acc, off);
    if (lane == 0) u1[row] = acc;
    return;
  }
  b -= 256;
  if (b < 256) {                        // cvv = Wv . bt + bv
    const int row = b * 4 + (tid >> 6);
    const int lane = tid & 63;
    float acc = 0.f;
#pragma unroll
    for (int j = 0; j < 16; ++j)
      acc = fmaf(Wv[(size_t)row * HDIM + lane + j * 64], bt[lane + j * 64], acc);
#pragma unroll
    for (int off = 32; off; off >>= 1) acc += __shfl_xor(acc, off);
    if (lane == 0) cvv[row] = acc + bv[row];
    return;
  }
  b -= 256;
  {                                     // qh -> qhb bf16, grid-stride over 4096 blocks
    for (long i = (long)b * 256 + tid; i < (long)MROWS * HDIM / 4; i += 4096L * 256) {
      const float4 f = *reinterpret_cast<const float4*>(qh + i * 4);
      u16 o[4] = {f2bf(f.x), f2bf(f.y), f2bf(f.z), f2bf(f.w)};
      *reinterpret_cast<ulong1*>(qhb + i * 4) = *reinterpret_cast<ulong1*>(o);
    }
  }
}

// ================= decompose / conv helpers =================
__global__ __launch_bounds__(256) void decompose3(
    const float* __restrict__ in, u16* __restrict__ H, u16* __restrict__ M, u16* __restrict__ L,
    long n4_total, long n4_valid)
{
  for (long i = blockIdx.x * 256 + threadIdx.x; i < n4_total; i += (long)gridDim.x * 256) {
    u16 oh[4] = {0,0,0,0}, om[4] = {0,0,0,0}, ol[4] = {0,0,0,0};
    if (i < n4_valid) {
      const float4 f = *reinterpret_cast<const float4*>(in + i * 4);
      const float xs[4] = {f.x, f.y, f.z, f.w};
#pragma unroll
      for (int k = 0; k < 4; ++k) split3(xs[k], oh[k], om[k], ol[k]);
    }
    *reinterpret_cast<ulong1*>(H + i * 4) = *reinterpret_cast<ulong1*>(oh);
    *reinterpret_cast<ulong1*>(M + i * 4) = *reinterpret_cast<ulong1*>(om);
    *reinterpret_cast<ulong1*>(L + i * 4) = *reinterpret_cast<ulong1*>(ol);
  }
}

__global__ __launch_bounds__(256) void conv2seg(
    const float* __restrict__ inA, u16* __restrict__ outA, long nb_a, long n4a_valid,
    const float* __restrict__ inB, u16* __restrict__ outB)
{
  const long b = blockIdx.x;
  const float* in; u16* out; long i;
  bool valid = true;
  if (b < nb_a) { in = inA; out = outA; i = b * 256 + threadIdx.x; valid = (i < n4a_valid); }
  else          { in = inB; out = outB; i = (b - nb_a) * 256 + threadIdx.x; }
  u16 o[4] = {0, 0, 0, 0};
  if (valid) {
    const float4 f = *reinterpret_cast<const float4*>(in + i * 4);
    o[0] = f2bf(f.x); o[1] = f2bf(f.y); o[2] = f2bf(f.z); o[3] = f2bf(f.w);
  }
  *reinterpret_cast<ulong1*>(out + i * 4) = *reinterpret_cast<ulong1*>(o);
}

// ================= bias-vector chain (dependent, tiny) =================
__global__ __launch_bounds__(256) void u2_k(
    const float* __restrict__ Wt, const float* __restrict__ u1, float* __restrict__ u2)
{
  const int row = blockIdx.x * 4 + (threadIdx.x >> 6);
  const int lane = threadIdx.x & 63;
  float acc = 0.f;
#pragma unroll
  for (int j = 0; j < 16; ++j)
    acc = fmaf(Wt[row + (size_t)(lane + j * 64) * EDIM], u1[lane + j * 64], acc);
#pragma unroll
  for (int off = 32; off; off >>= 1) acc += __shfl_xor(acc, off);
  if (lane == 0) u2[row] = acc;
}

__global__ __launch_bounds__(256) void cvec_k(
    const float* __restrict__ rel, const float* __restrict__ u2,
    const float* __restrict__ u1, const float* __restrict__ bt,
    const float* __restrict__ bk, const float* __restrict__ bq, float* __restrict__ cvec)
{
  const int row = blockIdx.x * 4 + (threadIdx.x >> 6);
  const int lane = threadIdx.x & 63;
  if (row >= R_REL) return;
  float acc = 0.f;
#pragma unroll
  for (int j = 0; j < 12; ++j)
    acc = fmaf(rel[(size_t)row * EDIM + lane + j * 64], u2[lane + j * 64], acc);
  float sac = 0.f;
#pragma unroll
  for (int j = 0; j < 16; ++j) {
    const int k = lane + j * 64;
    sac = fmaf(bt[k], u1[k], sac);
    sac = fmaf(bk[k], bq[k], sac);
  }
  acc += sac;
#pragma unroll
  for (int off = 32; off; off >>= 1) acc += __shfl_xor(acc, off);
  if (lane == 0) cvec[row] = acc;
}

__global__ __launch_bounds__(256) void w2bias_k(
    const float* __restrict__ T1f, const float* __restrict__ Wq,
    const float* __restrict__ bt, const float* __restrict__ bk, float* __restrict__ w2bias)
{
  const int row = blockIdx.x * 4 + (threadIdx.x >> 6);
  const int lane = threadIdx.x & 63;
  float acc = 0.f;
#pragma unroll
  for (int j = 0; j < 16; ++j) {
    const int k = lane + j * 64;
    acc = fmaf(T1f[(size_t)row * HDIM + k], bt[k], acc);
    acc = fmaf(Wq[row + (size_t)k * HDIM], bk[k], acc);
  }
#pragma unroll
  for (int off = 32; off; off >>= 1) acc += __shfl_xor(acc, off);
  if (lane == 0) w2bias[row] = acc;
}

// ====== PHASE A: pure-stream radix prefilter -> candidate lists ======
__global__ __launch_bounds__(64) void prefilter_k(
    const u16* __restrict__ Kt, u16* __restrict__ candidx, int* __restrict__ ncands)
{
  const int gm = blockIdx.x;
  const int lane = threadIdx.x;
  unsigned key[32];
  const u16* rowp = Kt + (size_t)gm * NPAD;
#pragma unroll
  for (int L = 0; L < 4; ++L) {
    const short8 v = *reinterpret_cast<const short8*>(rowp + lane * 8 + L * 512);
#pragma unroll
    for (int r = 0; r < 8; ++r) key[L * 8 + r] = (unsigned)(u16)v[r];
  }
  int lo = 1, hi = 65536;
  while (hi - lo > 1) {
    const int mid = (lo + hi) >> 1;
    int cnt = 0;
#pragma unroll
    for (int j = 0; j < 32; ++j)
      cnt += __popcll(__ballot(key[j] >= (unsigned)mid));
    if (cnt >= KSEL) lo = mid; else hi = mid;
  }
  const unsigned T = (unsigned)lo;
  int base = 0;
#pragma unroll
  for (int L = 0; L < 4; ++L) {
#pragma unroll
    for (int r = 0; r < 8; ++r) {
      const int j = L * 8 + r;
      const bool c = key[j] >= T;
      const unsigned long long m = __ballot(c);
      const int pre = __builtin_amdgcn_mbcnt_hi((unsigned)(m >> 32),
                      __builtin_amdgcn_mbcnt_lo((unsigned)m, 0));
      const int slot = base + pre;
      if (c && slot < CAP) candidx[(size_t)gm * CAP + slot] = (u16)(lane * 8 + r + L * 512);
      base += __popcll(m);
    }
  }
  if (lane == 0) ncands[gm] = (base < CAP) ? base : CAP;
}

// ====== PHASE B: cooperative 4-wave exact f32 rescore + bitonic top-28 + softmax ======
// 256 thr/row: wave wv rescans candidates c = wv, wv+4, ... (4 independent gather chains);
// scores meet in LDS; wave 0 sorts + softmaxes.
__global__ __launch_bounds__(256) void rescore_k(
    const u16* __restrict__ candidx, const int* __restrict__ ncands,
    const float* __restrict__ qh, const float* __restrict__ W2, const float* __restrict__ cvec,
    int* __restrict__ topidx, float* __restrict__ topw)
{
  const int gm = blockIdx.x;
  const int tid = threadIdx.x;
  const int wv = tid >> 6, lane = tid & 63;
  const int ncand = ncands[gm];
  __shared__ float s_sc[CAP];

  float q[16];
  {
    const float* qp = qh + (size_t)gm * HDIM + lane * 16;
#pragma unroll
    for (int v4 = 0; v4 < 4; ++v4) {
      const float4 f = *reinterpret_cast<const float4*>(qp + v4 * 4);
      q[v4 * 4 + 0] = f.x; q[v4 * 4 + 1] = f.y; q[v4 * 4 + 2] = f.z; q[v4 * 4 + 3] = f.w;
    }
  }
  for (int c = wv; c < ncand; c += 4) {
    const int r = candidx[(size_t)gm * CAP + c];
    const float* wp = W2 + (size_t)r * HDIM + lane * 16;
    float d = 0.f;
#pragma unroll
    for (int v4 = 0; v4 < 4; ++v4) {
      const float4 f = *reinterpret_cast<const float4*>(wp + v4 * 4);
      d = fmaf(q[v4 * 4 + 0], f.x, d);
      d = fmaf(q[v4 * 4 + 1], f.y, d);
      d = fmaf(q[v4 * 4 + 2], f.z, d);
      d = fmaf(q[v4 * 4 + 3], f.w, d);
    }
#pragma unroll
    for (int off = 32; off; off >>= 1) d += __shfl_xor(d, off);
    if (lane == 0) s_sc[c] = (d + cvec[r]) * 0.03125f;
  }
  __syncthreads();
  if (wv != 0) return;

  float myscore = -INFINITY;
  int myr = 0x7fffffff;
  if (lane < ncand) {
    myscore = s_sc[lane];
    myr = candidx[(size_t)gm * CAP + lane];
  }

  // bitonic sort 64 lanes, descending score, tie -> ascending index
#pragma unroll
  for (int k = 2; k <= 64; k <<= 1) {
#pragma unroll
    for (int j = k >> 1; j > 0; j >>= 1) {
      const float ov = __shfl_xor(myscore, j);
      const int oi = __shfl_xor(myr, j);
      const bool lower = (lane & j) == 0;
      const bool want_desc = (lane & k) == 0;
      const bool mine_better = (myscore > ov) || (myscore == ov && myr < oi);
      const bool keep = (lower == want_desc) ? mine_better : !mine_better;
      if (!keep) { myscore = ov; myr = oi; }
    }
  }

  const int nvalid = __popcll(__ballot(myscore > -INFINITY));
  const int nsel = (nvalid < TOPK) ? nvalid : TOPK;
  const float m0 = __shfl(myscore, 0);
  const float e = (lane < nsel) ? expf(myscore - m0) : 0.f;
  float z = e;
#pragma unroll
  for (int off = 32; off; off >>= 1) z += __shfl_xor(z, off);
  if (lane < TOPK) {
    topw[(size_t)gm * TOPK + lane] = (lane < nsel) ? (e / z) : 0.f;
    topidx[(size_t)gm * TOPK + lane] = (lane < nsel) ? myr : 0;
  }
}

// ====== PHASE C: sparse V-gather ======
__global__ __launch_bounds__(256) void out_gather(
    const int* __restrict__ topidx, const float* __restrict__ topw,
    const float* __restrict__ V, float* __restrict__ out)
{
  const int gm = blockIdx.x;
  const int tid = threadIdx.x;
  __shared__ float w[TOPK];
  __shared__ int   id[TOPK];
  if (tid < TOPK) {
    w[tid] = topw[(size_t)gm * TOPK + tid];
    id[tid] = topidx[(size_t)gm * TOPK + tid];
  }
  __syncthreads();
  float4 acc = make_float4(0.f, 0.f, 0.f, 0.f);
#pragma unroll 4
  for (int i = 0; i < TOPK; ++i) {
    const float wi = w[i];
    const float4 v = *reinterpret_cast<const float4*>(V + (size_t)id[i] * HDIM + tid * 4);
    acc.x = fmaf(wi, v.x, acc.x);
    acc.y = fmaf(wi, v.y, acc.y);
    acc.z = fmaf(wi, v.z, acc.z);
    acc.w = fmaf(wi, v.w, acc.w);
  }
  *reinterpret_cast<float4*>(out + (size_t)gm * HDIM + tid * 4) = acc;
}

extern "C" void kernel_launch(void* const* d_in, const int* in_sizes, int n_in,
                              void* d_out, int out_size, void* d_ws, size_t ws_size,
                              hipStream_t stream) {
  const float* qh  = (const float*)d_in[0];
  const void*  mask = d_in[1];
  const float* rel = (const float*)d_in[2];
  const int* f_i = (const int*)d_in[3];
  const int* f_j = (const int*)d_in[4];
  const float* Wt = (const float*)d_in[5]; const float* bt = (const float*)d_in[6];
  const float* Wq = (const float*)d_in[7]; const float* bq = (const float*)d_in[8];
  const float* Wk = (const float*)d_in[9]; const float* bk = (const float*)d_in[10];
  const float* Wv = (const float*)d_in[11]; const float* bv = (const float*)d_in[12];
  float* out = (float*)d_out;

  // ---- workspace layout with lifetime-based aliasing ----
  char* p = (char*)d_ws;
  auto alloc = [&](size_t bytes) { char* q_ = p; p += (bytes + 255) & ~(size_t)255; return q_; };
  float* W2   = (float*)alloc((size_t)R_REL * HDIM * 4);
  char* strip = alloc((size_t)(1024*1024 + 1024*768 + 1024*768) * 4);
  float* T1f = (float*)strip;
  float* Pf  = T1f + 1024 * 1024;
  float* Pvf = Pf + 1024 * 768;
  float* Vm  = (float*)strip;                   // alias (written after T1f/Pf/Pvf dead)
  u16* R1 = (u16*)alloc((size_t)3 * 1024 * 1024 * 2);   // WqT planes -> T1 planes
  u16* R2 = (u16*)alloc((size_t)3 * 1024 * 1024 * 2);   // WkT planes -> P planes
  u16* WtTp = (u16*)alloc((size_t)3 * 768 * 1024 * 2);
  u16* relp = (u16*)alloc((size_t)3 * MPADR * EDIM * 2);
  u16* qhb  = (u16*)alloc((size_t)MROWS * HDIM * 2);
  char* w2b_region = alloc((size_t)NPAD * HDIM * 2);
  u16* W2b  = (u16*)w2b_region;
  u16* Pv16 = (u16*)alloc((size_t)1024 * 768 * 2);
  u16* Kt   = (u16*)alloc((size_t)MROWS * NPAD * 2);
  u16* R3   = Kt;                               // Wv planes (dead before Kt written)
  u16* candidx = (u16*)alloc((size_t)MROWS * CAP * 2);
  int* ncands  = (int*)alloc((size_t)MROWS * 4);
  float* cvec   = (float*)alloc(NPAD * 4);
  float* u1     = (float*)alloc(1024 * 4);
  float* u2     = (float*)alloc(1024 * 4);
  float* w2bias = (float*)alloc(1024 * 4);
  float* cvv    = (float*)alloc(1024 * 4);
  unsigned long long* fbits = (unsigned long long*)alloc((size_t)MROWS * 8);
  unsigned* fij = (unsigned*)alloc(NPAD * 4);
  int* tidx = (int*)w2b_region;                 // alias (W2b dead after scores)
  float* tw = (float*)(w2b_region + (size_t)MROWS * TOPK * 4);

  const size_t PL1 = (size_t)1024 * 1024;
  const size_t PLW = (size_t)768 * 1024;
  const size_t PLR = (size_t)MPADR * EDIM;
  const size_t PLP = (size_t)1024 * 768;

  const dim3 blk(256);

  // 1: all independent early work in one launch
  mega_prep<<<dim3(14080), blk, 0, stream>>>(
      Wq, Wk, Wt, rel, Wv, qh, mask, f_i, f_j, bq, bt, bv,
      R1, R2, WtTp, relp, R3, qhb, fbits, fij, u1, cvv);

  // 2-3: dependent bias chain
  u2_k<<<dim3(192), blk, 0, stream>>>(Wt, u1, u2);
  cvec_k<<<dim3((R_REL + 3) / 4), blk, 0, stream>>>(rel, u2, u1, bt, bk, bq, cvec);

  // 4: T1 = Wq^T @ Wk  (bf16x3)
  x3gemm<3><<<dim3(1024/64, 1024/64, 1), blk, 0, stream>>>(
      R1, R1+PL1, R1+2*PL1, nullptr, nullptr, nullptr,
      R2, R2+PL1, R2+2*PL1, nullptr, nullptr, T1f, nullptr, 1024, 1024, 1024, 1024);
  // 5-6
  w2bias_k<<<dim3(256), blk, 0, stream>>>(T1f, Wq, bt, bk, w2bias);
  decompose3<<<dim3(1024), blk, 0, stream>>>(T1f, R1, R1+PL1, R1+2*PL1, (long)PL1/4, (long)PL1/4);
  // 7: P = T1 @ Wt  and  Pv = Wv @ Wt  (z-batched, shared B = WtT planes)
  x3gemm<3><<<dim3(768/64, 1024/64, 2), blk, 0, stream>>>(
      R1, R1+PL1, R1+2*PL1, R3, R3+PL1, R3+2*PL1,
      WtTp, WtTp+PLW, WtTp+2*PLW, nullptr, nullptr, Pf, Pvf, 1024, 768, 1024, 768);
  // 8
  decompose3<<<dim3(768), blk, 0, stream>>>(Pf, R2, R2+PLP, R2+2*PLP, (long)PLP/4, (long)PLP/4);
  // 9: W2 = rel @ P^T + w2bias
  x3gemm<3><<<dim3(1024/64, MPADR/64, 1), blk, 0, stream>>>(
      relp, relp+PLR, relp+2*PLR, nullptr, nullptr, nullptr,
      R2, R2+PLP, R2+2*PLP, w2bias, nullptr, W2, nullptr, EDIM, HDIM, R_REL, HDIM);

  // 10: W2b (padded) + Pv16 conversions in one launch
  conv2seg<<<dim3(2048 + 768), blk, 0, stream>>>(
      W2, W2b, 2048, (long)R_REL*HDIM/4, Pvf, Pv16);

  // 11: Vm = rel_h @ Pv16^T + cvv  (bf16; aliases the dead f32 strip)
  x3gemm<1><<<dim3(1024/64, MPADR/64, 1), blk, 0, stream>>>(
      relp, nullptr, nullptr, nullptr, nullptr, nullptr,
      Pv16, nullptr, nullptr, cvv, nullptr, Vm, nullptr, EDIM, HDIM, R_REL, HDIM);

  // 12: approx score keys, masked in epilogue (overwrites R3 region — Wv planes dead)
  mfma_scores128<<<dim3(NPAD/128, MROWS/128), blk, 0, stream>>>(
      qhb, W2b, cvec, fbits, fij, Kt, HDIM, R_REL);

  // 13-15: prefilter -> cooperative rescore -> gather
  prefilter_k<<<dim3(MROWS), dim3(64), 0, stream>>>(Kt, candidx, ncands);
  rescore_k<<<dim3(MROWS), blk, 0, stream>>>(candidx, ncands, qh, W2, cvec, tidx, tw);
  out_gather<<<dim3(MROWS), blk, 0, stream>>>(tidx, tw, Vm, out);
}

// Round 11
// 538.457 us; speedup vs baseline: 1.3063x; 1.1859x over previous
//
#include <hip/hip_runtime.h>
#include <hip/hip_bf16.h>

#define R_REL 2016
#define MROWS 16384
#define HDIM  1024
#define EDIM  768
#define TOPK  28
#define KSEL  31
#define CAP   48
#define NPAD  2048
#define MPADR 2048

typedef unsigned short u16;
typedef __attribute__((ext_vector_type(8))) short short8;
typedef __attribute__((ext_vector_type(4))) float f32x4;

__device__ inline float bf2f(u16 u) {
  unsigned x = ((unsigned)u) << 16; float f;
  __builtin_memcpy(&f, &x, 4); return f;
}
__device__ inline u16 f2bf(float f) {
  __hip_bfloat16 h = __float2bfloat16(f);
  u16 u; __builtin_memcpy(&u, &h, 2); return u;
}
__device__ inline void split3(float x, u16& h, u16& m, u16& l) {
  h = f2bf(x); const float r1 = x - bf2f(h);
  m = f2bf(r1); const float r2 = r1 - bf2f(m);
  l = f2bf(r2);
}
__device__ inline void gl2lds16(const void* g, void* l) {
  __builtin_amdgcn_global_load_lds((const __attribute__((address_space(1))) unsigned int*)g,
                                   (__attribute__((address_space(3))) unsigned int*)l, 16, 0, 0);
}

// ========== bf16x3 (or x1) NT GEMM, 64x64 tile, 4 waves, z-batched, fused epilogue ==========
// Per z: optional f32 out (C), bf16 out (Cb), 3-plane split out (Cp, stride pstr).
template<int PLANES>
__global__ __launch_bounds__(256) void x3gemm(
    const u16* __restrict__ Ah0, const u16* __restrict__ Am0, const u16* __restrict__ Al0,
    const u16* __restrict__ Ah1, const u16* __restrict__ Am1, const u16* __restrict__ Al1,
    const u16* __restrict__ Bh, const u16* __restrict__ Bm, const u16* __restrict__ Bl,
    const float* __restrict__ bias0, const float* __restrict__ bias1,
    float* __restrict__ C0, float* __restrict__ C1,
    u16* __restrict__ Cb0, u16* __restrict__ Cb1,
    u16* __restrict__ Cp0, u16* __restrict__ Cp1, long pstr,
    int K, int Nstride, int Mlim, int Nlim)
{
  __shared__ u16 lA[PLANES][64 * 32];
  __shared__ u16 lB[PLANES][64 * 32];
  const int zz = blockIdx.z;
  const u16* Ap[3] = { zz ? Ah1 : Ah0, zz ? Am1 : Am0, zz ? Al1 : Al0 };
  const u16* Bp[3] = {Bh, Bm, Bl};
  const float* bias = zz ? bias1 : bias0;
  float* C = zz ? C1 : C0;
  u16* Cb = zz ? Cb1 : Cb0;
  u16* Cp = zz ? Cp1 : Cp0;
  const int tid = threadIdx.x;
  const int wave = tid >> 6, lane = tid & 63;
  const int wr = wave >> 1, wc = wave & 1;
  const int row0 = blockIdx.y * 64, col0 = blockIdx.x * 64;

  f32x4 acc[2][2];
#pragma unroll
  for (int m = 0; m < 2; ++m)
#pragma unroll
    for (int n = 0; n < 2; ++n) acc[m][n] = (f32x4){0.f, 0.f, 0.f, 0.f};

  const int srow = lane >> 2, sslot = lane & 3;
  const int r15 = lane & 15, kq = lane >> 4;

  for (int k0 = 0; k0 < K; k0 += 32) {
    const int row = wave * 16 + srow;
    const int kg = sslot ^ ((row >> 1) & 3);
#pragma unroll
    for (int p = 0; p < PLANES; ++p) {
      gl2lds16(Ap[p] + (size_t)(row0 + row) * K + k0 + kg * 8, (u16*)lA[p] + wave * 512);
      gl2lds16(Bp[p] + (size_t)(col0 + row) * K + k0 + kg * 8, (u16*)lB[p] + wave * 512);
    }
    __syncthreads();
    short8 a[PLANES][2], b[PLANES][2];
#pragma unroll
    for (int m = 0; m < 2; ++m) {
      const int rowL = wr * 32 + m * 16 + r15;
      const int slot = kq ^ ((rowL >> 1) & 3);
#pragma unroll
      for (int p = 0; p < PLANES; ++p)
        a[p][m] = *reinterpret_cast<const short8*>(&lA[p][rowL * 32 + slot * 8]);
    }
#pragma unroll
    for (int n = 0; n < 2; ++n) {
      const int colL = wc * 32 + n * 16 + r15;
      const int slot = kq ^ ((colL >> 1) & 3);
#pragma unroll
      for (int p = 0; p < PLANES; ++p)
        b[p][n] = *reinterpret_cast<const short8*>(&lB[p][colL * 32 + slot * 8]);
    }
#pragma unroll
    for (int m = 0; m < 2; ++m)
#pragma unroll
      for (int n = 0; n < 2; ++n) {
        if constexpr (PLANES == 3) {
          acc[m][n] = __builtin_amdgcn_mfma_f32_16x16x32_bf16(a[2][m], b[0][n], acc[m][n], 0, 0, 0);
          acc[m][n] = __builtin_amdgcn_mfma_f32_16x16x32_bf16(a[0][m], b[2][n], acc[m][n], 0, 0, 0);
          acc[m][n] = __builtin_amdgcn_mfma_f32_16x16x32_bf16(a[1][m], b[1][n], acc[m][n], 0, 0, 0);
          acc[m][n] = __builtin_amdgcn_mfma_f32_16x16x32_bf16(a[1][m], b[0][n], acc[m][n], 0, 0, 0);
          acc[m][n] = __builtin_amdgcn_mfma_f32_16x16x32_bf16(a[0][m], b[1][n], acc[m][n], 0, 0, 0);
          acc[m][n] = __builtin_amdgcn_mfma_f32_16x16x32_bf16(a[0][m], b[0][n], acc[m][n], 0, 0, 0);
        } else {
          acc[m][n] = __builtin_amdgcn_mfma_f32_16x16x32_bf16(a[0][m], b[0][n], acc[m][n], 0, 0, 0);
        }
      }
    __syncthreads();
  }
  const int quad = lane >> 4;
#pragma unroll
  for (int m = 0; m < 2; ++m)
#pragma unroll
    for (int n = 0; n < 2; ++n) {
      const int cg = col0 + wc * 32 + n * 16 + r15;
      if (cg >= Nlim) continue;
      const float ev = bias ? bias[cg] : 0.f;
#pragma unroll
      for (int reg = 0; reg < 4; ++reg) {
        const int rg = row0 + wr * 32 + m * 16 + quad * 4 + reg;
        if (rg >= Mlim) continue;
        const float v = acc[m][n][reg] + ev;
        const size_t o = (size_t)rg * Nstride + cg;
        if (C) C[o] = v;
        if (Cb) Cb[o] = f2bf(v);
        if (Cp) {
          u16 hh, mm2, ll; split3(v, hh, mm2, ll);
          Cp[o] = hh; Cp[o + pstr] = mm2; Cp[o + 2 * pstr] = ll;
        }
      }
    }
}

// ============ scores MFMA (128x128, BK=32, XCD-swizzled) ============
// Kt = key((A@B^T + cvec)/32) with mask applied in epilogue; masked/pad -> key 0.
__global__ __launch_bounds__(256) void mfma_scores128(
    const u16* __restrict__ A, const u16* __restrict__ B,
    const float* __restrict__ cvec, const unsigned long long* __restrict__ fbits,
    const unsigned* __restrict__ fij, u16* __restrict__ Kt, int K, int Nlim)
{
  __shared__ u16 ldsA[128 * 32];
  __shared__ u16 ldsB[128 * 32];
  const int tid = threadIdx.x;
  const int wave = tid >> 6, lane = tid & 63;
  const int wr = wave >> 1, wc = wave & 1;
  unsigned wg = blockIdx.y * gridDim.x + blockIdx.x;
  const unsigned per = (gridDim.x * gridDim.y) >> 3;
  wg = (wg & 7) * per + (wg >> 3);
  const int row0 = (int)(wg / gridDim.x) * 128, col0 = (int)(wg % gridDim.x) * 128;

  f32x4 acc[4][4];
#pragma unroll
  for (int m = 0; m < 4; ++m)
#pragma unroll
    for (int n = 0; n < 4; ++n) acc[m][n] = (f32x4){0.f, 0.f, 0.f, 0.f};

  const int srow = lane >> 2, sslot = lane & 3;

  for (int k0 = 0; k0 < K; k0 += 32) {
#pragma unroll
    for (int j = 0; j < 2; ++j) {
      const int row = (wave * 2 + j) * 16 + srow;
      const int kg = sslot ^ ((row >> 1) & 3);
      gl2lds16(A + (size_t)(row0 + row) * K + k0 + kg * 8, (char*)ldsA + (size_t)(wave * 2 + j) * 1024);
      gl2lds16(B + (size_t)(col0 + row) * K + k0 + kg * 8, (char*)ldsB + (size_t)(wave * 2 + j) * 1024);
    }
    __syncthreads();
    const int r15 = lane & 15, kq = lane >> 4;
    short8 a[4], b[4];
#pragma unroll
    for (int m = 0; m < 4; ++m) {
      const int rowL = wr * 64 + m * 16 + r15;
      const int slot = kq ^ ((rowL >> 1) & 3);
      a[m] = *reinterpret_cast<const short8*>(&ldsA[rowL * 32 + slot * 8]);
    }
#pragma unroll
    for (int n = 0; n < 4; ++n) {
      const int colL = wc * 64 + n * 16 + r15;
      const int slot = kq ^ ((colL >> 1) & 3);
      b[n] = *reinterpret_cast<const short8*>(&ldsB[colL * 32 + slot * 8]);
    }
#pragma unroll
    for (int m = 0; m < 4; ++m)
#pragma unroll
      for (int n = 0; n < 4; ++n)
        acc[m][n] = __builtin_amdgcn_mfma_f32_16x16x32_bf16(a[m], b[n], acc[m][n], 0, 0, 0);
    __syncthreads();
  }
  const int r15 = lane & 15, quad = lane >> 4;
#pragma unroll
  for (int m = 0; m < 4; ++m) {
    const int rgb = row0 + wr * 64 + m * 16 + quad * 4;
    unsigned long long fbr[4];
#pragma unroll
    for (int reg = 0; reg < 4; ++reg) fbr[reg] = fbits[rgb + reg];
#pragma unroll
    for (int n = 0; n < 4; ++n) {
      const int cg = col0 + wc * 64 + n * 16 + r15;
      const bool vc = (cg < Nlim);
      const float cv = vc ? cvec[cg] : 0.f;
      const unsigned pp = vc ? fij[cg] : 0u;
      const unsigned fi = pp & 63u, fj = pp >> 16;
#pragma unroll
      for (int reg = 0; reg < 4; ++reg) {
        u16 okey = 0;
        if (vc && ((((fbr[reg] >> fi) & (fbr[reg] >> fj)) & 1ULL) != 0)) {
          const float s = (acc[m][n][reg] + cv) * 0.03125f;
          const u16 u = f2bf(s);
          okey = (u & 0x8000) ? (u16)(~u) : (u16)(u | 0x8000);
        }
        __builtin_nontemporal_store(okey, &Kt[(size_t)(rgb + reg) * NPAD + cg]);
      }
    }
  }
}

// ================= MEGA-PREP: all independent early conversions in one launch =================
__global__ __launch_bounds__(256) void mega_prep(
    const float* __restrict__ Wq, const float* __restrict__ Wk, const float* __restrict__ Wt,
    const float* __restrict__ rel, const float* __restrict__ Wv, const float* __restrict__ qh,
    const void* __restrict__ mask, const int* __restrict__ f_i, const int* __restrict__ f_j,
    const float* __restrict__ bq, const float* __restrict__ bt, const float* __restrict__ bv,
    u16* __restrict__ R1, u16* __restrict__ R2, u16* __restrict__ WtTp,
    u16* __restrict__ relp, u16* __restrict__ R3, u16* __restrict__ qhb,
    unsigned long long* __restrict__ fbits, unsigned* __restrict__ fij,
    float* __restrict__ u1, float* __restrict__ cvv)
{
  __shared__ float t[32][33];
  const int tid = threadIdx.x;
  int b = blockIdx.x;
  const size_t PL1 = (size_t)1024 * 1024;
  const size_t PLW = (size_t)768 * 1024;
  const size_t PLR = (size_t)MPADR * EDIM;

  if (b < 2048) {                       // Wq / Wk transpose-decompose -> R1 / R2
    const float* in = (b < 1024) ? Wq : Wk;
    u16* H = (b < 1024) ? R1 : R2;
    const int bb = b & 1023;
    const int bx = bb & 31, by = bb >> 5;
    const int x = tid & 31, y = tid >> 5;
#pragma unroll
    for (int yy = 0; yy < 4; ++yy)
      t[y + yy * 8][x] = in[(size_t)(by * 32 + y + yy * 8) * 1024 + bx * 32 + x];
    __syncthreads();
#pragma unroll
    for (int yy = 0; yy < 4; ++yy) {
      u16 h, m, l; split3(t[x][y + yy * 8], h, m, l);
      const size_t o = (size_t)(bx * 32 + y + yy * 8) * 1024 + by * 32 + x;
      H[o] = h; H[o + PL1] = m; H[o + 2 * PL1] = l;
    }
    return;
  }
  b -= 2048;
  if (b < 768) {                        // Wt [1024][768] -> WtTp [768][1024] x3
    const int bx = b % 24, by = b / 24;
    const int x = tid & 31, y = tid >> 5;
#pragma unroll
    for (int yy = 0; yy < 4; ++yy)
      t[y + yy * 8][x] = Wt[(size_t)(by * 32 + y + yy * 8) * 768 + bx * 32 + x];
    __syncthreads();
#pragma unroll
    for (int yy = 0; yy < 4; ++yy) {
      u16 h, m, l; split3(t[x][y + yy * 8], h, m, l);
      const size_t o = (size_t)(bx * 32 + y + yy * 8) * 1024 + by * 32 + x;
      WtTp[o] = h; WtTp[o + PLW] = m; WtTp[o + 2 * PLW] = l;
    }
    return;
  }
  b -= 768;
  if (b < 1536) {                       // rel decompose3 -> relp (pad rows zero)
    const long i = (long)b * 256 + tid;
    const long nvalid = (long)R_REL * EDIM / 4;
    u16 oh[4] = {0,0,0,0}, om[4] = {0,0,0,0}, ol[4] = {0,0,0,0};
    if (i < nvalid) {
      const float4 f = *reinterpret_cast<const float4*>(rel + i * 4);
      const float xs[4] = {f.x, f.y, f.z, f.w};
#pragma unroll
      for (int k = 0; k < 4; ++k) split3(xs[k], oh[k], om[k], ol[k]);
    }
    *reinterpret_cast<ulong1*>(relp + i * 4)           = *reinterpret_cast<ulong1*>(oh);
    *reinterpret_cast<ulong1*>(relp + PLR + i * 4)     = *reinterpret_cast<ulong1*>(om);
    *reinterpret_cast<ulong1*>(relp + 2 * PLR + i * 4) = *reinterpret_cast<ulong1*>(ol);
    return;
  }
  b -= 1536;
  if (b < 1024) {                       // Wv decompose3 -> R3 planes
    const long i = (long)b * 256 + tid;
    const float4 f = *reinterpret_cast<const float4*>(Wv + i * 4);
    const float xs[4] = {f.x, f.y, f.z, f.w};
    u16 oh[4], om[4], ol[4];
#pragma unroll
    for (int k = 0; k < 4; ++k) split3(xs[k], oh[k], om[k], ol[k]);
    *reinterpret_cast<ulong1*>(R3 + i * 4)           = *reinterpret_cast<ulong1*>(oh);
    *reinterpret_cast<ulong1*>(R3 + PL1 + i * 4)     = *reinterpret_cast<ulong1*>(om);
    *reinterpret_cast<ulong1*>(R3 + 2 * PL1 + i * 4) = *reinterpret_cast<ulong1*>(ol);
    return;
  }
  b -= 1024;
  if (b < 4096) {                       // fbits (self-detecting kind) + fij
    const int gm = b * 4 + (tid >> 6);
    const int lane = tid & 63;
    const unsigned* mw = (const unsigned*)mask;
    bool sawf = false, sawg = false;
#pragma unroll
    for (int k = 0; k < 4; ++k) {
      const unsigned w = mw[lane * 4 + k];
      sawf |= (w == 0x3F800000u);
      sawg |= (w > 1u);
    }
    const int kind = __ballot(sawf) ? 2 : (__ballot(sawg) ? 1 : 0);
    const size_t e = (size_t)gm * 64 + lane;
    bool on;
    if (kind == 0)      on = ((const int*)mask)[e] != 0;
    else if (kind == 1) on = ((const unsigned char*)mask)[e] != 0;
    else                on = ((const float*)mask)[e] != 0.f;
    const unsigned long long bb = __ballot(on);
    if (lane == 0) fbits[gm] = bb;
    if (b < 8) {
      const int i = b * 256 + tid;
      const int src = (i < R_REL) ? i : (R_REL - 1);
      fij[i] = ((unsigned)f_i[src] & 0xFFFFu) | (((unsigned)f_j[src] & 0xFFFFu) << 16);
    }
    return;
  }
  b -= 4096;
  if (b < 256) {                        // u1 = Wk^T . bq
    const int row = b * 4 + (tid >> 6);
    const int lane = tid & 63;
    float acc = 0.f;
#pragma unroll
    for (int j = 0; j < 16; ++j)
      acc = fmaf(Wk[row + (size_t)(lane + j * 64) * HDIM], bq[lane + j * 64], acc);
#pragma unroll
    for (int off = 32; off; off >>= 1) acc += __shfl_xor(acc, off);
    if (lane == 0) u1[row] = acc;
    return;
  }
  b -= 256;
  if (b < 256) {                        // cvv = Wv . bt + bv
    const int row = b * 4 + (tid >> 6);
    const int lane = tid & 63;
    float acc = 0.f;
#pragma unroll
    for (int j = 0; j < 16; ++j)
      acc = fmaf(Wv[(size_t)row * HDIM + lane + j * 64], bt[lane + j * 64], acc);
#pragma unroll
    for (int off = 32; off; off >>= 1) acc += __shfl_xor(acc, off);
    if (lane == 0) cvv[row] = acc + bv[row];
    return;
  }
  b -= 256;
  {                                     // qh -> qhb bf16, grid-stride over 4096 blocks
    for (long i = (long)b * 256 + tid; i < (long)MROWS * HDIM / 4; i += 4096L * 256) {
      const float4 f = *reinterpret_cast<const float4*>(qh + i * 4);
      u16 o[4] = {f2bf(f.x), f2bf(f.y), f2bf(f.z), f2bf(f.w)};
      *reinterpret_cast<ulong1*>(qhb + i * 4) = *reinterpret_cast<ulong1*>(o);
    }
  }
}

// ================= bias-vector chain (dependent, tiny) =================
__global__ __launch_bounds__(256) void u2_k(
    const float* __restrict__ Wt, const float* __restrict__ u1, float* __restrict__ u2)
{
  const int row = blockIdx.x * 4 + (threadIdx.x >> 6);
  const int lane = threadIdx.x & 63;
  float acc = 0.f;
#pragma unroll
  for (int j = 0; j < 16; ++j)
    acc = fmaf(Wt[row + (size_t)(lane + j * 64) * EDIM], u1[lane + j * 64], acc);
#pragma unroll
  for (int off = 32; off; off >>= 1) acc += __shfl_xor(acc, off);
  if (lane == 0) u2[row] = acc;
}

__global__ __launch_bounds__(256) void cvec_k(
    const float* __restrict__ rel, const float* __restrict__ u2,
    const float* __restrict__ u1, const float* __restrict__ bt,
    const float* __restrict__ bk, const float* __restrict__ bq, float* __restrict__ cvec)
{
  const int row = blockIdx.x * 4 + (threadIdx.x >> 6);
  const int lane = threadIdx.x & 63;
  if (row >= R_REL) return;
  float acc = 0.f;
#pragma unroll
  for (int j = 0; j < 12; ++j)
    acc = fmaf(rel[(size_t)row * EDIM + lane + j * 64], u2[lane + j * 64], acc);
  float sac = 0.f;
#pragma unroll
  for (int j = 0; j < 16; ++j) {
    const int k = lane + j * 64;
    sac = fmaf(bt[k], u1[k], sac);
    sac = fmaf(bk[k], bq[k], sac);
  }
  acc += sac;
#pragma unroll
  for (int off = 32; off; off >>= 1) acc += __shfl_xor(acc, off);
  if (lane == 0) cvec[row] = acc;
}

__global__ __launch_bounds__(256) void w2bias_k(
    const float* __restrict__ T1f, const float* __restrict__ Wq,
    const float* __restrict__ bt, const float* __restrict__ bk, float* __restrict__ w2bias)
{
  const int row = blockIdx.x * 4 + (threadIdx.x >> 6);
  const int lane = threadIdx.x & 63;
  float acc = 0.f;
#pragma unroll
  for (int j = 0; j < 16; ++j) {
    const int k = lane + j * 64;
    acc = fmaf(T1f[(size_t)row * HDIM + k], bt[k], acc);
    acc = fmaf(Wq[row + (size_t)k * HDIM], bk[k], acc);
  }
#pragma unroll
  for (int off = 32; off; off >>= 1) acc += __shfl_xor(acc, off);
  if (lane == 0) w2bias[row] = acc;
}

// ====== PHASE A: pure-stream radix prefilter -> candidate lists ======
__global__ __launch_bounds__(64) void prefilter_k(
    const u16* __restrict__ Kt, u16* __restrict__ candidx, int* __restrict__ ncands)
{
  const int gm = blockIdx.x;
  const int lane = threadIdx.x;
  unsigned key[32];
  const u16* rowp = Kt + (size_t)gm * NPAD;
#pragma unroll
  for (int L = 0; L < 4; ++L) {
    const short8 v = *reinterpret_cast<const short8*>(rowp + lane * 8 + L * 512);
#pragma unroll
    for (int r = 0; r < 8; ++r) key[L * 8 + r] = (unsigned)(u16)v[r];
  }
  int lo = 1, hi = 65536;
  while (hi - lo > 1) {
    const int mid = (lo + hi) >> 1;
    int cnt = 0;
#pragma unroll
    for (int j = 0; j < 32; ++j)
      cnt += __popcll(__ballot(key[j] >= (unsigned)mid));
    if (cnt >= KSEL) lo = mid; else hi = mid;
  }
  const unsigned T = (unsigned)lo;
  int base = 0;
#pragma unroll
  for (int L = 0; L < 4; ++L) {
#pragma unroll
    for (int r = 0; r < 8; ++r) {
      const int j = L * 8 + r;
      const bool c = key[j] >= T;
      const unsigned long long m = __ballot(c);
      const int pre = __builtin_amdgcn_mbcnt_hi((unsigned)(m >> 32),
                      __builtin_amdgcn_mbcnt_lo((unsigned)m, 0));
      const int slot = base + pre;
      if (c && slot < CAP) candidx[(size_t)gm * CAP + slot] = (u16)(lane * 8 + r + L * 512);
      base += __popcll(m);
    }
  }
  if (lane == 0) ncands[gm] = (base < CAP) ? base : CAP;
}

// ====== PHASE B: serial exact f32 rescore (r8 form) + bitonic top-28 + softmax ======
__global__ __launch_bounds__(64) void rescore_k(
    const u16* __restrict__ candidx, const int* __restrict__ ncands,
    const float* __restrict__ qh, const float* __restrict__ W2, const float* __restrict__ cvec,
    int* __restrict__ topidx, float* __restrict__ topw)
{
  const int gm = blockIdx.x;
  const int lane = threadIdx.x;
  const int ncand = ncands[gm];
  int myr = 0x7fffffff;
  if (lane < ncand) myr = candidx[(size_t)gm * CAP + lane];

  float q[16];
  {
    const float* qp = qh + (size_t)gm * HDIM + lane * 16;
#pragma unroll
    for (int v4 = 0; v4 < 4; ++v4) {
      const float4 f = *reinterpret_cast<const float4*>(qp + v4 * 4);
      q[v4 * 4 + 0] = f.x; q[v4 * 4 + 1] = f.y; q[v4 * 4 + 2] = f.z; q[v4 * 4 + 3] = f.w;
    }
  }
  float myscore = -INFINITY;
  for (int c = 0; c < CAP; ++c) {
    if (c >= ncand) break;
    const int r = __shfl(myr, c);
    const float* wp = W2 + (size_t)r * HDIM + lane * 16;
    float d = 0.f;
#pragma unroll
    for (int v4 = 0; v4 < 4; ++v4) {
      const float4 f = *reinterpret_cast<const float4*>(wp + v4 * 4);
      d = fmaf(q[v4 * 4 + 0], f.x, d);
      d = fmaf(q[v4 * 4 + 1], f.y, d);
      d = fmaf(q[v4 * 4 + 2], f.z, d);
      d = fmaf(q[v4 * 4 + 3], f.w, d);
    }
#pragma unroll
    for (int off = 32; off; off >>= 1) d += __shfl_xor(d, off);
    const float s = (d + cvec[r]) * 0.03125f;
    if (lane == c) myscore = s;
  }

  // bitonic sort 64 lanes, descending score, tie -> ascending index
#pragma unroll
  for (int k = 2; k <= 64; k <<= 1) {
#pragma unroll
    for (int j = k >> 1; j > 0; j >>= 1) {
      const float ov = __shfl_xor(myscore, j);
      const int oi = __shfl_xor(myr, j);
      const bool lower = (lane & j) == 0;
      const bool want_desc = (lane & k) == 0;
      const bool mine_better = (myscore > ov) || (myscore == ov && myr < oi);
      const bool keep = (lower == want_desc) ? mine_better : !mine_better;
      if (!keep) { myscore = ov; myr = oi; }
    }
  }

  const int nvalid = __popcll(__ballot(myscore > -INFINITY));
  const int nsel = (nvalid < TOPK) ? nvalid : TOPK;
  const float m0 = __shfl(myscore, 0);
  const float e = (lane < nsel) ? expf(myscore - m0) : 0.f;
  float z = e;
#pragma unroll
  for (int off = 32; off; off >>= 1) z += __shfl_xor(z, off);
  if (lane < TOPK) {
    topw[(size_t)gm * TOPK + lane] = (lane < nsel) ? (e / z) : 0.f;
    topidx[(size_t)gm * TOPK + lane] = (lane < nsel) ? myr : 0;
  }
}

// ====== PHASE C: sparse V-gather (bf16 Vm -> half the gather bytes) ======
__global__ __launch_bounds__(256) void out_gather(
    const int* __restrict__ topidx, const float* __restrict__ topw,
    const u16* __restrict__ V16, float* __restrict__ out)
{
  const int gm = blockIdx.x;
  const int tid = threadIdx.x;
  __shared__ float w[TOPK];
  __shared__ int   id[TOPK];
  if (tid < TOPK) {
    w[tid] = topw[(size_t)gm * TOPK + tid];
    id[tid] = topidx[(size_t)gm * TOPK + tid];
  }
  __syncthreads();
  float4 acc = make_float4(0.f, 0.f, 0.f, 0.f);
#pragma unroll 4
  for (int i = 0; i < TOPK; ++i) {
    const float wi = w[i];
    const ushort4 v = *reinterpret_cast<const ushort4*>(V16 + (size_t)id[i] * HDIM + tid * 4);
    acc.x = fmaf(wi, bf2f(v.x), acc.x);
    acc.y = fmaf(wi, bf2f(v.y), acc.y);
    acc.z = fmaf(wi, bf2f(v.z), acc.z);
    acc.w = fmaf(wi, bf2f(v.w), acc.w);
  }
  *reinterpret_cast<float4*>(out + (size_t)gm * HDIM + tid * 4) = acc;
}

extern "C" void kernel_launch(void* const* d_in, const int* in_sizes, int n_in,
                              void* d_out, int out_size, void* d_ws, size_t ws_size,
                              hipStream_t stream) {
  const float* qh  = (const float*)d_in[0];
  const void*  mask = d_in[1];
  const float* rel = (const float*)d_in[2];
  const int* f_i = (const int*)d_in[3];
  const int* f_j = (const int*)d_in[4];
  const float* Wt = (const float*)d_in[5]; const float* bt = (const float*)d_in[6];
  const float* Wq = (const float*)d_in[7]; const float* bq = (const float*)d_in[8];
  const float* Wk = (const float*)d_in[9]; const float* bk = (const float*)d_in[10];
  const float* Wv = (const float*)d_in[11]; const float* bv = (const float*)d_in[12];
  float* out = (float*)d_out;

  // ---- workspace layout with lifetime-based aliasing ----
  char* p = (char*)d_ws;
  auto alloc = [&](size_t bytes) { char* q_ = p; p += (bytes + 255) & ~(size_t)255; return q_; };
  float* W2   = (float*)alloc((size_t)R_REL * HDIM * 4);
  float* T1f  = (float*)alloc((size_t)1024 * 1024 * 4);
  u16* Vm16   = (u16*)alloc((size_t)MPADR * HDIM * 2);
  u16* T1p    = (u16*)alloc((size_t)3 * 1024 * 1024 * 2);   // T1 planes (separate from R1!)
  u16* R1 = (u16*)alloc((size_t)3 * 1024 * 1024 * 2);       // WqT planes
  u16* R2 = (u16*)alloc((size_t)3 * 1024 * 1024 * 2);       // WkT planes -> P planes
  u16* WtTp = (u16*)alloc((size_t)3 * 768 * 1024 * 2);
  u16* relp = (u16*)alloc((size_t)3 * MPADR * EDIM * 2);
  u16* qhb  = (u16*)alloc((size_t)MROWS * HDIM * 2);
  char* w2b_region = alloc((size_t)NPAD * HDIM * 2);
  u16* W2b  = (u16*)w2b_region;
  u16* Pv16 = (u16*)alloc((size_t)1024 * 768 * 2);
  u16* Kt   = (u16*)alloc((size_t)MROWS * NPAD * 2);
  u16* R3   = Kt;                               // Wv planes (dead before Kt written)
  u16* candidx = (u16*)alloc((size_t)MROWS * CAP * 2);
  int* ncands  = (int*)alloc((size_t)MROWS * 4);
  float* cvec   = (float*)alloc(NPAD * 4);
  float* u1     = (float*)alloc(1024 * 4);
  float* u2     = (float*)alloc(1024 * 4);
  float* w2bias = (float*)alloc(1024 * 4);
  float* cvv    = (float*)alloc(1024 * 4);
  unsigned long long* fbits = (unsigned long long*)alloc((size_t)MROWS * 8);
  unsigned* fij = (unsigned*)alloc(NPAD * 4);
  int* tidx = (int*)w2b_region;                 // alias (W2b dead after scores)
  float* tw = (float*)(w2b_region + (size_t)MROWS * TOPK * 4);

  const size_t PL1 = (size_t)1024 * 1024;
  const size_t PLW = (size_t)768 * 1024;
  const size_t PLR = (size_t)MPADR * EDIM;
  const size_t PLP = (size_t)1024 * 768;

  const dim3 blk(256);

  // 1: all independent early work in one launch
  mega_prep<<<dim3(14080), blk, 0, stream>>>(
      Wq, Wk, Wt, rel, Wv, qh, mask, f_i, f_j, bq, bt, bv,
      R1, R2, WtTp, relp, R3, qhb, fbits, fij, u1, cvv);

  // 2-3: dependent bias chain
  u2_k<<<dim3(192), blk, 0, stream>>>(Wt, u1, u2);
  cvec_k<<<dim3((R_REL + 3) / 4), blk, 0, stream>>>(rel, u2, u1, bt, bk, bq, cvec);

  // 4: T1 = Wq^T @ Wk  (bf16x3) -> f32 T1f + planes T1p (fused epilogue)
  x3gemm<3><<<dim3(1024/64, 1024/64, 1), blk, 0, stream>>>(
      R1, R1+PL1, R1+2*PL1, nullptr, nullptr, nullptr,
      R2, R2+PL1, R2+2*PL1, nullptr, nullptr,
      T1f, nullptr, nullptr, nullptr, T1p, nullptr, (long)PL1,
      1024, 1024, 1024, 1024);
  // 5: w2bias from T1f
  w2bias_k<<<dim3(256), blk, 0, stream>>>(T1f, Wq, bt, bk, w2bias);
  // 6: P = T1 @ Wt -> planes R2 ; Pv = Wv @ Wt -> bf16 Pv16  (z-batched)
  x3gemm<3><<<dim3(768/64, 1024/64, 2), blk, 0, stream>>>(
      T1p, T1p+PL1, T1p+2*PL1, R3, R3+PL1, R3+2*PL1,
      WtTp, WtTp+PLW, WtTp+2*PLW, nullptr, nullptr,
      nullptr, nullptr, nullptr, Pv16, R2, nullptr, (long)PLP,
      1024, 768, 1024, 768);
  // 7: W2 = rel @ P^T + w2bias -> f32 W2 + bf16 W2b (fused epilogue)
  x3gemm<3><<<dim3(1024/64, MPADR/64, 1), blk, 0, stream>>>(
      relp, relp+PLR, relp+2*PLR, nullptr, nullptr, nullptr,
      R2, R2+PLP, R2+2*PLP, w2bias, nullptr,
      W2, nullptr, W2b, nullptr, nullptr, nullptr, 0,
      EDIM, HDIM, R_REL, HDIM);

  // 8: Vm16 = bf16(rel_h @ Pv16^T + cvv)
  x3gemm<1><<<dim3(1024/64, MPADR/64, 1), blk, 0, stream>>>(
      relp, nullptr, nullptr, nullptr, nullptr, nullptr,
      Pv16, nullptr, nullptr, cvv, nullptr,
      nullptr, nullptr, Vm16, nullptr, nullptr, nullptr, 0,
      EDIM, HDIM, R_REL, HDIM);

  // 9: approx score keys, masked in epilogue (overwrites R3 region — Wv planes dead)
  mfma_scores128<<<dim3(NPAD/128, MROWS/128), blk, 0, stream>>>(
      qhb, W2b, cvec, fbits, fij, Kt, HDIM, R_REL);

  // 10-12: prefilter -> serial rescore (r8 form) -> bf16 V-gather
  prefilter_k<<<dim3(MROWS), dim3(64), 0, stream>>>(Kt, candidx, ncands);
  rescore_k<<<dim3(MROWS), dim3(64), 0, stream>>>(candidx, ncands, qh, W2, cvec, tidx, tw);
  out_gather<<<dim3(MROWS), blk, 0, stream>>>(tidx, tw, Vm16, out);
}

// Round 12
// 520.036 us; speedup vs baseline: 1.3526x; 1.0354x over previous
//
#include <hip/hip_runtime.h>
#include <hip/hip_bf16.h>

#define R_REL 2016
#define MROWS 16384
#define HDIM  1024
#define EDIM  768
#define TOPK  28
#define KSEL  31
#define CAP   48
#define NPAD  2048
#define MPADR 2048

typedef unsigned short u16;
typedef __attribute__((ext_vector_type(8))) short short8;
typedef __attribute__((ext_vector_type(8))) unsigned short ushort8;
typedef __attribute__((ext_vector_type(4))) float f32x4;

__device__ inline float bf2f(u16 u) {
  unsigned x = ((unsigned)u) << 16; float f;
  __builtin_memcpy(&f, &x, 4); return f;
}
__device__ inline u16 f2bf(float f) {
  __hip_bfloat16 h = __float2bfloat16(f);
  u16 u; __builtin_memcpy(&u, &h, 2); return u;
}
__device__ inline void split3(float x, u16& h, u16& m, u16& l) {
  h = f2bf(x); const float r1 = x - bf2f(h);
  m = f2bf(r1); const float r2 = r1 - bf2f(m);
  l = f2bf(r2);
}
__device__ inline void gl2lds16(const void* g, void* l) {
  __builtin_amdgcn_global_load_lds((const __attribute__((address_space(1))) unsigned int*)g,
                                   (__attribute__((address_space(3))) unsigned int*)l, 16, 0, 0);
}

// ========== bf16x3 (or x1) NT GEMM, 64x64 tile, 4 waves, z-batched, fused epilogue ==========
// Per z: optional f32 out (C), bf16 out (Cb), 3-plane split out (Cp, stride pstr).
template<int PLANES>
__global__ __launch_bounds__(256) void x3gemm(
    const u16* __restrict__ Ah0, const u16* __restrict__ Am0, const u16* __restrict__ Al0,
    const u16* __restrict__ Ah1, const u16* __restrict__ Am1, const u16* __restrict__ Al1,
    const u16* __restrict__ Bh, const u16* __restrict__ Bm, const u16* __restrict__ Bl,
    const float* __restrict__ bias0, const float* __restrict__ bias1,
    float* __restrict__ C0, float* __restrict__ C1,
    u16* __restrict__ Cb0, u16* __restrict__ Cb1,
    u16* __restrict__ Cp0, u16* __restrict__ Cp1, long pstr,
    int K, int Nstride, int Mlim, int Nlim)
{
  __shared__ u16 lA[PLANES][64 * 32];
  __shared__ u16 lB[PLANES][64 * 32];
  const int zz = blockIdx.z;
  const u16* Ap[3] = { zz ? Ah1 : Ah0, zz ? Am1 : Am0, zz ? Al1 : Al0 };
  const u16* Bp[3] = {Bh, Bm, Bl};
  const float* bias = zz ? bias1 : bias0;
  float* C = zz ? C1 : C0;
  u16* Cb = zz ? Cb1 : Cb0;
  u16* Cp = zz ? Cp1 : Cp0;
  const int tid = threadIdx.x;
  const int wave = tid >> 6, lane = tid & 63;
  const int wr = wave >> 1, wc = wave & 1;
  const int row0 = blockIdx.y * 64, col0 = blockIdx.x * 64;

  f32x4 acc[2][2];
#pragma unroll
  for (int m = 0; m < 2; ++m)
#pragma unroll
    for (int n = 0; n < 2; ++n) acc[m][n] = (f32x4){0.f, 0.f, 0.f, 0.f};

  const int srow = lane >> 2, sslot = lane & 3;
  const int r15 = lane & 15, kq = lane >> 4;

  for (int k0 = 0; k0 < K; k0 += 32) {
    const int row = wave * 16 + srow;
    const int kg = sslot ^ ((row >> 1) & 3);
#pragma unroll
    for (int p = 0; p < PLANES; ++p) {
      gl2lds16(Ap[p] + (size_t)(row0 + row) * K + k0 + kg * 8, (u16*)lA[p] + wave * 512);
      gl2lds16(Bp[p] + (size_t)(col0 + row) * K + k0 + kg * 8, (u16*)lB[p] + wave * 512);
    }
    __syncthreads();
    short8 a[PLANES][2], b[PLANES][2];
#pragma unroll
    for (int m = 0; m < 2; ++m) {
      const int rowL = wr * 32 + m * 16 + r15;
      const int slot = kq ^ ((rowL >> 1) & 3);
#pragma unroll
      for (int p = 0; p < PLANES; ++p)
        a[p][m] = *reinterpret_cast<const short8*>(&lA[p][rowL * 32 + slot * 8]);
    }
#pragma unroll
    for (int n = 0; n < 2; ++n) {
      const int colL = wc * 32 + n * 16 + r15;
      const int slot = kq ^ ((colL >> 1) & 3);
#pragma unroll
      for (int p = 0; p < PLANES; ++p)
        b[p][n] = *reinterpret_cast<const short8*>(&lB[p][colL * 32 + slot * 8]);
    }
#pragma unroll
    for (int m = 0; m < 2; ++m)
#pragma unroll
      for (int n = 0; n < 2; ++n) {
        if constexpr (PLANES == 3) {
          acc[m][n] = __builtin_amdgcn_mfma_f32_16x16x32_bf16(a[2][m], b[0][n], acc[m][n], 0, 0, 0);
          acc[m][n] = __builtin_amdgcn_mfma_f32_16x16x32_bf16(a[0][m], b[2][n], acc[m][n], 0, 0, 0);
          acc[m][n] = __builtin_amdgcn_mfma_f32_16x16x32_bf16(a[1][m], b[1][n], acc[m][n], 0, 0, 0);
          acc[m][n] = __builtin_amdgcn_mfma_f32_16x16x32_bf16(a[1][m], b[0][n], acc[m][n], 0, 0, 0);
          acc[m][n] = __builtin_amdgcn_mfma_f32_16x16x32_bf16(a[0][m], b[1][n], acc[m][n], 0, 0, 0);
          acc[m][n] = __builtin_amdgcn_mfma_f32_16x16x32_bf16(a[0][m], b[0][n], acc[m][n], 0, 0, 0);
        } else {
          acc[m][n] = __builtin_amdgcn_mfma_f32_16x16x32_bf16(a[0][m], b[0][n], acc[m][n], 0, 0, 0);
        }
      }
    __syncthreads();
  }
  const int quad = lane >> 4;
#pragma unroll
  for (int m = 0; m < 2; ++m)
#pragma unroll
    for (int n = 0; n < 2; ++n) {
      const int cg = col0 + wc * 32 + n * 16 + r15;
      if (cg >= Nlim) continue;
      const float ev = bias ? bias[cg] : 0.f;
#pragma unroll
      for (int reg = 0; reg < 4; ++reg) {
        const int rg = row0 + wr * 32 + m * 16 + quad * 4 + reg;
        if (rg >= Mlim) continue;
        const float v = acc[m][n][reg] + ev;
        const size_t o = (size_t)rg * Nstride + cg;
        if (C) C[o] = v;
        if (Cb) Cb[o] = f2bf(v);
        if (Cp) {
          u16 hh, mm2, ll; split3(v, hh, mm2, ll);
          Cp[o] = hh; Cp[o + pstr] = mm2; Cp[o + 2 * pstr] = ll;
        }
      }
    }
}

// ============ scores MFMA (128x128, BK=32, XCD-swizzled, 2-phase double-buffered) ============
// Kt = key((A@B^T + cvec)/32) with mask applied in epilogue; masked/pad -> key 0.
__global__ __launch_bounds__(256) void mfma_scores128(
    const u16* __restrict__ A, const u16* __restrict__ B,
    const float* __restrict__ cvec, const unsigned long long* __restrict__ fbits,
    const unsigned* __restrict__ fij, u16* __restrict__ Kt, int K, int Nlim)
{
  __shared__ u16 ldsA[2][128 * 32];
  __shared__ u16 ldsB[2][128 * 32];
  const int tid = threadIdx.x;
  const int wave = tid >> 6, lane = tid & 63;
  const int wr = wave >> 1, wc = wave & 1;
  unsigned wg = blockIdx.y * gridDim.x + blockIdx.x;
  const unsigned per = (gridDim.x * gridDim.y) >> 3;
  wg = (wg & 7) * per + (wg >> 3);
  const int row0 = (int)(wg / gridDim.x) * 128, col0 = (int)(wg % gridDim.x) * 128;

  f32x4 acc[4][4];
#pragma unroll
  for (int m = 0; m < 4; ++m)
#pragma unroll
    for (int n = 0; n < 4; ++n) acc[m][n] = (f32x4){0.f, 0.f, 0.f, 0.f};

  const int srow = lane >> 2, sslot = lane & 3;

  auto stage = [&](int buf, int k0) {
#pragma unroll
    for (int j = 0; j < 2; ++j) {
      const int row = (wave * 2 + j) * 16 + srow;
      const int kg = sslot ^ ((row >> 1) & 3);
      gl2lds16(A + (size_t)(row0 + row) * K + k0 + kg * 8,
               (char*)ldsA[buf] + (size_t)(wave * 2 + j) * 1024);
      gl2lds16(B + (size_t)(col0 + row) * K + k0 + kg * 8,
               (char*)ldsB[buf] + (size_t)(wave * 2 + j) * 1024);
    }
  };

  stage(0, 0);
  __syncthreads();                 // drains vmcnt(0): buf0 ready
  int cur = 0;
  for (int k0 = 0; k0 < K; k0 += 32) {
    if (k0 + 32 < K) stage(cur ^ 1, k0 + 32);   // prefetch next tile (async, other buffer)
    const int r15 = lane & 15, kq = lane >> 4;
    short8 a[4], b[4];
#pragma unroll
    for (int m = 0; m < 4; ++m) {
      const int rowL = wr * 64 + m * 16 + r15;
      const int slot = kq ^ ((rowL >> 1) & 3);
      a[m] = *reinterpret_cast<const short8*>(&ldsA[cur][rowL * 32 + slot * 8]);
    }
#pragma unroll
    for (int n = 0; n < 4; ++n) {
      const int colL = wc * 64 + n * 16 + r15;
      const int slot = kq ^ ((colL >> 1) & 3);
      b[n] = *reinterpret_cast<const short8*>(&ldsB[cur][colL * 32 + slot * 8]);
    }
#pragma unroll
    for (int m = 0; m < 4; ++m)
#pragma unroll
      for (int n = 0; n < 4; ++n)
        acc[m][n] = __builtin_amdgcn_mfma_f32_16x16x32_bf16(a[m], b[n], acc[m][n], 0, 0, 0);
    __syncthreads();               // drains vmcnt(0)+lgkmcnt: prefetch landed, reads done
    cur ^= 1;
  }
  const int r15 = lane & 15, quad = lane >> 4;
#pragma unroll
  for (int m = 0; m < 4; ++m) {
    const int rgb = row0 + wr * 64 + m * 16 + quad * 4;
    unsigned long long fbr[4];
#pragma unroll
    for (int reg = 0; reg < 4; ++reg) fbr[reg] = fbits[rgb + reg];
#pragma unroll
    for (int n = 0; n < 4; ++n) {
      const int cg = col0 + wc * 64 + n * 16 + r15;
      const bool vc = (cg < Nlim);
      const float cv = vc ? cvec[cg] : 0.f;
      const unsigned pp = vc ? fij[cg] : 0u;
      const unsigned fi = pp & 63u, fj = pp >> 16;
#pragma unroll
      for (int reg = 0; reg < 4; ++reg) {
        u16 okey = 0;
        if (vc && ((((fbr[reg] >> fi) & (fbr[reg] >> fj)) & 1ULL) != 0)) {
          const float s = (acc[m][n][reg] + cv) * 0.03125f;
          const u16 u = f2bf(s);
          okey = (u & 0x8000) ? (u16)(~u) : (u16)(u | 0x8000);
        }
        __builtin_nontemporal_store(okey, &Kt[(size_t)(rgb + reg) * NPAD + cg]);
      }
    }
  }
}

// ================= MEGA-PREP: all independent early conversions in one launch =================
__global__ __launch_bounds__(256) void mega_prep(
    const float* __restrict__ Wq, const float* __restrict__ Wk, const float* __restrict__ Wt,
    const float* __restrict__ rel, const float* __restrict__ Wv, const float* __restrict__ qh,
    const void* __restrict__ mask, const int* __restrict__ f_i, const int* __restrict__ f_j,
    const float* __restrict__ bq, const float* __restrict__ bt, const float* __restrict__ bv,
    u16* __restrict__ R1, u16* __restrict__ R2, u16* __restrict__ WtTp,
    u16* __restrict__ relp, u16* __restrict__ R3, u16* __restrict__ qhb,
    unsigned long long* __restrict__ fbits, unsigned* __restrict__ fij,
    float* __restrict__ u1, float* __restrict__ cvv)
{
  __shared__ float t[32][33];
  const int tid = threadIdx.x;
  int b = blockIdx.x;
  const size_t PL1 = (size_t)1024 * 1024;
  const size_t PLW = (size_t)768 * 1024;
  const size_t PLR = (size_t)MPADR * EDIM;

  if (b < 2048) {                       // Wq / Wk transpose-decompose -> R1 / R2
    const float* in = (b < 1024) ? Wq : Wk;
    u16* H = (b < 1024) ? R1 : R2;
    const int bb = b & 1023;
    const int bx = bb & 31, by = bb >> 5;
    const int x = tid & 31, y = tid >> 5;
#pragma unroll
    for (int yy = 0; yy < 4; ++yy)
      t[y + yy * 8][x] = in[(size_t)(by * 32 + y + yy * 8) * 1024 + bx * 32 + x];
    __syncthreads();
#pragma unroll
    for (int yy = 0; yy < 4; ++yy) {
      u16 h, m, l; split3(t[x][y + yy * 8], h, m, l);
      const size_t o = (size_t)(bx * 32 + y + yy * 8) * 1024 + by * 32 + x;
      H[o] = h; H[o + PL1] = m; H[o + 2 * PL1] = l;
    }
    return;
  }
  b -= 2048;
  if (b < 768) {                        // Wt [1024][768] -> WtTp [768][1024] x3
    const int bx = b % 24, by = b / 24;
    const int x = tid & 31, y = tid >> 5;
#pragma unroll
    for (int yy = 0; yy < 4; ++yy)
      t[y + yy * 8][x] = Wt[(size_t)(by * 32 + y + yy * 8) * 768 + bx * 32 + x];
    __syncthreads();
#pragma unroll
    for (int yy = 0; yy < 4; ++yy) {
      u16 h, m, l; split3(t[x][y + yy * 8], h, m, l);
      const size_t o = (size_t)(bx * 32 + y + yy * 8) * 1024 + by * 32 + x;
      WtTp[o] = h; WtTp[o + PLW] = m; WtTp[o + 2 * PLW] = l;
    }
    return;
  }
  b -= 768;
  if (b < 1536) {                       // rel decompose3 -> relp (pad rows zero)
    const long i = (long)b * 256 + tid;
    const long nvalid = (long)R_REL * EDIM / 4;
    u16 oh[4] = {0,0,0,0}, om[4] = {0,0,0,0}, ol[4] = {0,0,0,0};
    if (i < nvalid) {
      const float4 f = *reinterpret_cast<const float4*>(rel + i * 4);
      const float xs[4] = {f.x, f.y, f.z, f.w};
#pragma unroll
      for (int k = 0; k < 4; ++k) split3(xs[k], oh[k], om[k], ol[k]);
    }
    *reinterpret_cast<ulong1*>(relp + i * 4)           = *reinterpret_cast<ulong1*>(oh);
    *reinterpret_cast<ulong1*>(relp + PLR + i * 4)     = *reinterpret_cast<ulong1*>(om);
    *reinterpret_cast<ulong1*>(relp + 2 * PLR + i * 4) = *reinterpret_cast<ulong1*>(ol);
    return;
  }
  b -= 1536;
  if (b < 1024) {                       // Wv decompose3 -> R3 planes
    const long i = (long)b * 256 + tid;
    const float4 f = *reinterpret_cast<const float4*>(Wv + i * 4);
    const float xs[4] = {f.x, f.y, f.z, f.w};
    u16 oh[4], om[4], ol[4];
#pragma unroll
    for (int k = 0; k < 4; ++k) split3(xs[k], oh[k], om[k], ol[k]);
    *reinterpret_cast<ulong1*>(R3 + i * 4)           = *reinterpret_cast<ulong1*>(oh);
    *reinterpret_cast<ulong1*>(R3 + PL1 + i * 4)     = *reinterpret_cast<ulong1*>(om);
    *reinterpret_cast<ulong1*>(R3 + 2 * PL1 + i * 4) = *reinterpret_cast<ulong1*>(ol);
    return;
  }
  b -= 1024;
  if (b < 4096) {                       // fbits (self-detecting kind) + fij
    const int gm = b * 4 + (tid >> 6);
    const int lane = tid & 63;
    const unsigned* mw = (const unsigned*)mask;
    bool sawf = false, sawg = false;
#pragma unroll
    for (int k = 0; k < 4; ++k) {
      const unsigned w = mw[lane * 4 + k];
      sawf |= (w == 0x3F800000u);
      sawg |= (w > 1u);
    }
    const int kind = __ballot(sawf) ? 2 : (__ballot(sawg) ? 1 : 0);
    const size_t e = (size_t)gm * 64 + lane;
    bool on;
    if (kind == 0)      on = ((const int*)mask)[e] != 0;
    else if (kind == 1) on = ((const unsigned char*)mask)[e] != 0;
    else                on = ((const float*)mask)[e] != 0.f;
    const unsigned long long bb = __ballot(on);
    if (lane == 0) fbits[gm] = bb;
    if (b < 8) {
      const int i = b * 256 + tid;
      const int src = (i < R_REL) ? i : (R_REL - 1);
      fij[i] = ((unsigned)f_i[src] & 0xFFFFu) | (((unsigned)f_j[src] & 0xFFFFu) << 16);
    }
    return;
  }
  b -= 4096;
  if (b < 256) {                        // u1 = Wk^T . bq
    const int row = b * 4 + (tid >> 6);
    const int lane = tid & 63;
    float acc = 0.f;
#pragma unroll
    for (int j = 0; j < 16; ++j)
      acc = fmaf(Wk[row + (size_t)(lane + j * 64) * HDIM], bq[lane + j * 64], acc);
#pragma unroll
    for (int off = 32; off; off >>= 1) acc += __shfl_xor(acc, off);
    if (lane == 0) u1[row] = acc;
    return;
  }
  b -= 256;
  if (b < 256) {                        // cvv = Wv . bt + bv
    const int row = b * 4 + (tid >> 6);
    const int lane = tid & 63;
    float acc = 0.f;
#pragma unroll
    for (int j = 0; j < 16; ++j)
      acc = fmaf(Wv[(size_t)row * HDIM + lane + j * 64], bt[lane + j * 64], acc);
#pragma unroll
    for (int off = 32; off; off >>= 1) acc += __shfl_xor(acc, off);
    if (lane == 0) cvv[row] = acc + bv[row];
    return;
  }
  b -= 256;
  {                                     // qh -> qhb bf16, grid-stride over 4096 blocks
    for (long i = (long)b * 256 + tid; i < (long)MROWS * HDIM / 4; i += 4096L * 256) {
      const float4 f = *reinterpret_cast<const float4*>(qh + i * 4);
      u16 o[4] = {f2bf(f.x), f2bf(f.y), f2bf(f.z), f2bf(f.w)};
      *reinterpret_cast<ulong1*>(qhb + i * 4) = *reinterpret_cast<ulong1*>(o);
    }
  }
}

// ================= bias-vector chain (dependent, tiny) =================
__global__ __launch_bounds__(256) void u2_k(
    const float* __restrict__ Wt, const float* __restrict__ u1, float* __restrict__ u2)
{
  const int row = blockIdx.x * 4 + (threadIdx.x >> 6);
  const int lane = threadIdx.x & 63;
  float acc = 0.f;
#pragma unroll
  for (int j = 0; j < 16; ++j)
    acc = fmaf(Wt[row + (size_t)(lane + j * 64) * EDIM], u1[lane + j * 64], acc);
#pragma unroll
  for (int off = 32; off; off >>= 1) acc += __shfl_xor(acc, off);
  if (lane == 0) u2[row] = acc;
}

__global__ __launch_bounds__(256) void cvec_k(
    const float* __restrict__ rel, const float* __restrict__ u2,
    const float* __restrict__ u1, const float* __restrict__ bt,
    const float* __restrict__ bk, const float* __restrict__ bq, float* __restrict__ cvec)
{
  const int row = blockIdx.x * 4 + (threadIdx.x >> 6);
  const int lane = threadIdx.x & 63;
  if (row >= R_REL) return;
  float acc = 0.f;
#pragma unroll
  for (int j = 0; j < 12; ++j)
    acc = fmaf(rel[(size_t)row * EDIM + lane + j * 64], u2[lane + j * 64], acc);
  float sac = 0.f;
#pragma unroll
  for (int j = 0; j < 16; ++j) {
    const int k = lane + j * 64;
    sac = fmaf(bt[k], u1[k], sac);
    sac = fmaf(bk[k], bq[k], sac);
  }
  acc += sac;
#pragma unroll
  for (int off = 32; off; off >>= 1) acc += __shfl_xor(acc, off);
  if (lane == 0) cvec[row] = acc;
}

__global__ __launch_bounds__(256) void w2bias_k(
    const float* __restrict__ T1f, const float* __restrict__ Wq,
    const float* __restrict__ bt, const float* __restrict__ bk, float* __restrict__ w2bias)
{
  const int row = blockIdx.x * 4 + (threadIdx.x >> 6);
  const int lane = threadIdx.x & 63;
  float acc = 0.f;
#pragma unroll
  for (int j = 0; j < 16; ++j) {
    const int k = lane + j * 64;
    acc = fmaf(T1f[(size_t)row * HDIM + k], bt[k], acc);
    acc = fmaf(Wq[row + (size_t)k * HDIM], bk[k], acc);
  }
#pragma unroll
  for (int off = 32; off; off >>= 1) acc += __shfl_xor(acc, off);
  if (lane == 0) w2bias[row] = acc;
}

// ====== PHASE A: radix prefilter, 4 rows/block (256 thr) ======
__global__ __launch_bounds__(256) void prefilter_k(
    const u16* __restrict__ Kt, u16* __restrict__ candidx, int* __restrict__ ncands)
{
  const int gm = blockIdx.x * 4 + (threadIdx.x >> 6);
  const int lane = threadIdx.x & 63;
  unsigned key[32];
  const u16* rowp = Kt + (size_t)gm * NPAD;
#pragma unroll
  for (int L = 0; L < 4; ++L) {
    const short8 v = *reinterpret_cast<const short8*>(rowp + lane * 8 + L * 512);
#pragma unroll
    for (int r = 0; r < 8; ++r) key[L * 8 + r] = (unsigned)(u16)v[r];
  }
  int lo = 1, hi = 65536;
  while (hi - lo > 1) {
    const int mid = (lo + hi) >> 1;
    int cnt = 0;
#pragma unroll
    for (int j = 0; j < 32; ++j)
      cnt += __popcll(__ballot(key[j] >= (unsigned)mid));
    if (cnt >= KSEL) lo = mid; else hi = mid;
  }
  const unsigned T = (unsigned)lo;
  int base = 0;
#pragma unroll
  for (int L = 0; L < 4; ++L) {
#pragma unroll
    for (int r = 0; r < 8; ++r) {
      const int j = L * 8 + r;
      const bool c = key[j] >= T;
      const unsigned long long m = __ballot(c);
      const int pre = __builtin_amdgcn_mbcnt_hi((unsigned)(m >> 32),
                      __builtin_amdgcn_mbcnt_lo((unsigned)m, 0));
      const int slot = base + pre;
      if (c && slot < CAP) candidx[(size_t)gm * CAP + slot] = (u16)(lane * 8 + r + L * 512);
      base += __popcll(m);
    }
  }
  if (lane == 0) ncands[gm] = (base < CAP) ? base : CAP;
}

// ====== PHASE B: serial exact f32 rescore (r8 form) + bitonic top-28 + softmax ======
__global__ __launch_bounds__(64) void rescore_k(
    const u16* __restrict__ candidx, const int* __restrict__ ncands,
    const float* __restrict__ qh, const float* __restrict__ W2, const float* __restrict__ cvec,
    int* __restrict__ topidx, float* __restrict__ topw)
{
  const int gm = blockIdx.x;
  const int lane = threadIdx.x;
  const int ncand = ncands[gm];
  int myr = 0x7fffffff;
  if (lane < ncand) myr = candidx[(size_t)gm * CAP + lane];

  float q[16];
  {
    const float* qp = qh + (size_t)gm * HDIM + lane * 16;
#pragma unroll
    for (int v4 = 0; v4 < 4; ++v4) {
      const float4 f = *reinterpret_cast<const float4*>(qp + v4 * 4);
      q[v4 * 4 + 0] = f.x; q[v4 * 4 + 1] = f.y; q[v4 * 4 + 2] = f.z; q[v4 * 4 + 3] = f.w;
    }
  }
  float myscore = -INFINITY;
  for (int c = 0; c < CAP; ++c) {
    if (c >= ncand) break;
    const int r = __shfl(myr, c);
    const float* wp = W2 + (size_t)r * HDIM + lane * 16;
    float d = 0.f;
#pragma unroll
    for (int v4 = 0; v4 < 4; ++v4) {
      const float4 f = *reinterpret_cast<const float4*>(wp + v4 * 4);
      d = fmaf(q[v4 * 4 + 0], f.x, d);
      d = fmaf(q[v4 * 4 + 1], f.y, d);
      d = fmaf(q[v4 * 4 + 2], f.z, d);
      d = fmaf(q[v4 * 4 + 3], f.w, d);
    }
#pragma unroll
    for (int off = 32; off; off >>= 1) d += __shfl_xor(d, off);
    const float s = (d + cvec[r]) * 0.03125f;
    if (lane == c) myscore = s;
  }

  // bitonic sort 64 lanes, descending score, tie -> ascending index
#pragma unroll
  for (int k = 2; k <= 64; k <<= 1) {
#pragma unroll
    for (int j = k >> 1; j > 0; j >>= 1) {
      const float ov = __shfl_xor(myscore, j);
      const int oi = __shfl_xor(myr, j);
      const bool lower = (lane & j) == 0;
      const bool want_desc = (lane & k) == 0;
      const bool mine_better = (myscore > ov) || (myscore == ov && myr < oi);
      const bool keep = (lower == want_desc) ? mine_better : !mine_better;
      if (!keep) { myscore = ov; myr = oi; }
    }
  }

  const int nvalid = __popcll(__ballot(myscore > -INFINITY));
  const int nsel = (nvalid < TOPK) ? nvalid : TOPK;
  const float m0 = __shfl(myscore, 0);
  const float e = (lane < nsel) ? expf(myscore - m0) : 0.f;
  float z = e;
#pragma unroll
  for (int off = 32; off; off >>= 1) z += __shfl_xor(z, off);
  if (lane < TOPK) {
    topw[(size_t)gm * TOPK + lane] = (lane < nsel) ? (e / z) : 0.f;
    topidx[(size_t)gm * TOPK + lane] = (lane < nsel) ? myr : 0;
  }
}

// ====== PHASE C: sparse V-gather, 2 rows/block, 128 thr/row, ushort8 loads ======
__global__ __launch_bounds__(256) void out_gather(
    const int* __restrict__ topidx, const float* __restrict__ topw,
    const u16* __restrict__ V16, float* __restrict__ out)
{
  const int half = threadIdx.x >> 7;
  const int t = threadIdx.x & 127;
  const int gm = blockIdx.x * 2 + half;
  __shared__ float w[2][TOPK];
  __shared__ int   id[2][TOPK];
  if (t < TOPK) {
    w[half][t] = topw[(size_t)gm * TOPK + t];
    id[half][t] = topidx[(size_t)gm * TOPK + t];
  }
  __syncthreads();
  float acc[8] = {0.f, 0.f, 0.f, 0.f, 0.f, 0.f, 0.f, 0.f};
#pragma unroll 4
  for (int i = 0; i < TOPK; ++i) {
    const float wi = w[half][i];
    const ushort8 v = *reinterpret_cast<const ushort8*>(V16 + (size_t)id[half][i] * HDIM + t * 8);
#pragma unroll
    for (int j = 0; j < 8; ++j) acc[j] = fmaf(wi, bf2f(v[j]), acc[j]);
  }
  float* op = out + (size_t)gm * HDIM + t * 8;
  *reinterpret_cast<float4*>(op)     = make_float4(acc[0], acc[1], acc[2], acc[3]);
  *reinterpret_cast<float4*>(op + 4) = make_float4(acc[4], acc[5], acc[6], acc[7]);
}

extern "C" void kernel_launch(void* const* d_in, const int* in_sizes, int n_in,
                              void* d_out, int out_size, void* d_ws, size_t ws_size,
                              hipStream_t stream) {
  const float* qh  = (const float*)d_in[0];
  const void*  mask = d_in[1];
  const float* rel = (const float*)d_in[2];
  const int* f_i = (const int*)d_in[3];
  const int* f_j = (const int*)d_in[4];
  const float* Wt = (const float*)d_in[5]; const float* bt = (const float*)d_in[6];
  const float* Wq = (const float*)d_in[7]; const float* bq = (const float*)d_in[8];
  const float* Wk = (const float*)d_in[9]; const float* bk = (const float*)d_in[10];
  const float* Wv = (const float*)d_in[11]; const float* bv = (const float*)d_in[12];
  float* out = (float*)d_out;

  // ---- workspace layout with lifetime-based aliasing ----
  char* p = (char*)d_ws;
  auto alloc = [&](size_t bytes) { char* q_ = p; p += (bytes + 255) & ~(size_t)255; return q_; };
  float* W2   = (float*)alloc((size_t)R_REL * HDIM * 4);
  float* T1f  = (float*)alloc((size_t)1024 * 1024 * 4);
  u16* Vm16   = (u16*)alloc((size_t)MPADR * HDIM * 2);
  u16* T1p    = (u16*)alloc((size_t)3 * 1024 * 1024 * 2);   // T1 planes (separate from R1!)
  u16* R1 = (u16*)alloc((size_t)3 * 1024 * 1024 * 2);       // WqT planes
  u16* R2 = (u16*)alloc((size_t)3 * 1024 * 1024 * 2);       // WkT planes -> P planes
  u16* WtTp = (u16*)alloc((size_t)3 * 768 * 1024 * 2);
  u16* relp = (u16*)alloc((size_t)3 * MPADR * EDIM * 2);
  u16* qhb  = (u16*)alloc((size_t)MROWS * HDIM * 2);
  char* w2b_region = alloc((size_t)NPAD * HDIM * 2);
  u16* W2b  = (u16*)w2b_region;
  u16* Pv16 = (u16*)alloc((size_t)1024 * 768 * 2);
  u16* Kt   = (u16*)alloc((size_t)MROWS * NPAD * 2);
  u16* R3   = Kt;                               // Wv planes (dead before Kt written)
  u16* candidx = (u16*)alloc((size_t)MROWS * CAP * 2);
  int* ncands  = (int*)alloc((size_t)MROWS * 4);
  float* cvec   = (float*)alloc(NPAD * 4);
  float* u1     = (float*)alloc(1024 * 4);
  float* u2     = (float*)alloc(1024 * 4);
  float* w2bias = (float*)alloc(1024 * 4);
  float* cvv    = (float*)alloc(1024 * 4);
  unsigned long long* fbits = (unsigned long long*)alloc((size_t)MROWS * 8);
  unsigned* fij = (unsigned*)alloc(NPAD * 4);
  int* tidx = (int*)w2b_region;                 // alias (W2b dead after scores)
  float* tw = (float*)(w2b_region + (size_t)MROWS * TOPK * 4);

  const size_t PL1 = (size_t)1024 * 1024;
  const size_t PLW = (size_t)768 * 1024;
  const size_t PLR = (size_t)MPADR * EDIM;
  const size_t PLP = (size_t)1024 * 768;

  const dim3 blk(256);

  // 1: all independent early work in one launch
  mega_prep<<<dim3(14080), blk, 0, stream>>>(
      Wq, Wk, Wt, rel, Wv, qh, mask, f_i, f_j, bq, bt, bv,
      R1, R2, WtTp, relp, R3, qhb, fbits, fij, u1, cvv);

  // 2-3: dependent bias chain
  u2_k<<<dim3(192), blk, 0, stream>>>(Wt, u1, u2);
  cvec_k<<<dim3((R_REL + 3) / 4), blk, 0, stream>>>(rel, u2, u1, bt, bk, bq, cvec);

  // 4: T1 = Wq^T @ Wk  (bf16x3) -> f32 T1f + planes T1p (fused epilogue)
  x3gemm<3><<<dim3(1024/64, 1024/64, 1), blk, 0, stream>>>(
      R1, R1+PL1, R1+2*PL1, nullptr, nullptr, nullptr,
      R2, R2+PL1, R2+2*PL1, nullptr, nullptr,
      T1f, nullptr, nullptr, nullptr, T1p, nullptr, (long)PL1,
      1024, 1024, 1024, 1024);
  // 5: w2bias from T1f
  w2bias_k<<<dim3(256), blk, 0, stream>>>(T1f, Wq, bt, bk, w2bias);
  // 6: P = T1 @ Wt -> planes R2 ; Pv = Wv @ Wt -> bf16 Pv16  (z-batched)
  x3gemm<3><<<dim3(768/64, 1024/64, 2), blk, 0, stream>>>(
      T1p, T1p+PL1, T1p+2*PL1, R3, R3+PL1, R3+2*PL1,
      WtTp, WtTp+PLW, WtTp+2*PLW, nullptr, nullptr,
      nullptr, nullptr, nullptr, Pv16, R2, nullptr, (long)PLP,
      1024, 768, 1024, 768);
  // 7: W2 = rel @ P^T + w2bias -> f32 W2 + bf16 W2b (fused epilogue)
  x3gemm<3><<<dim3(1024/64, MPADR/64, 1), blk, 0, stream>>>(
      relp, relp+PLR, relp+2*PLR, nullptr, nullptr, nullptr,
      R2, R2+PLP, R2+2*PLP, w2bias, nullptr,
      W2, nullptr, W2b, nullptr, nullptr, nullptr, 0,
      EDIM, HDIM, R_REL, HDIM);

  // 8: Vm16 = bf16(rel_h @ Pv16^T + cvv)
  x3gemm<1><<<dim3(1024/64, MPADR/64, 1), blk, 0, stream>>>(
      relp, nullptr, nullptr, nullptr, nullptr, nullptr,
      Pv16, nullptr, nullptr, cvv, nullptr,
      nullptr, nullptr, Vm16, nullptr, nullptr, nullptr, 0,
      EDIM, HDIM, R_REL, HDIM);

  // 9: approx score keys, masked in epilogue (overwrites R3 region — Wv planes dead)
  mfma_scores128<<<dim3(NPAD/128, MROWS/128), blk, 0, stream>>>(
      qhb, W2b, cvec, fbits, fij, Kt, HDIM, R_REL);

  // 10-12: prefilter -> serial rescore -> bf16 V-gather
  prefilter_k<<<dim3(MROWS / 4), blk, 0, stream>>>(Kt, candidx, ncands);
  rescore_k<<<dim3(MROWS), dim3(64), 0, stream>>>(candidx, ncands, qh, W2, cvec, tidx, tw);
  out_gather<<<dim3(MROWS / 2), blk, 0, stream>>>(tidx, tw, Vm16, out);
}